// Round 1
// baseline (564.620 us; speedup 1.0000x reference)
//
#include <hip/hip_runtime.h>
#include <cstdint>
#include <cstddef>

#define N_ATOMS 20000
#define F_DIM 1920
#define H_DIM 512
#define S_NUM 3
#define NSTRUCT_ 16

typedef __bf16 bf16;
typedef __bf16 bf16x4 __attribute__((ext_vector_type(4)));
typedef __bf16 bf16x8 __attribute__((ext_vector_type(8)));
typedef float f32x4 __attribute__((ext_vector_type(4)));

__device__ __forceinline__ void gload_lds16(const void* g, void* l) {
  __builtin_amdgcn_global_load_lds(
      (const __attribute__((address_space(1))) unsigned int*)g,
      (__attribute__((address_space(3))) unsigned int*)l, 16, 0, 0);
}

// ---------------- routing / setup kernels ----------------

__global__ void init_kernel(float* e_perm, float* out, int* ints) {
  int i = blockIdx.x * 256 + threadIdx.x;
  if (i < N_ATOMS) e_perm[i] = 0.f;
  if (i < NSTRUCT_) out[i] = 0.f;
  if (i < 6) ints[i] = 0;  // cnt[0..2], pos[0..2]
}

__global__ void count_kernel(const int* __restrict__ species, int* cnt) {
  int i = blockIdx.x * 256 + threadIdx.x;
  if (i < N_ATOMS) atomicAdd(&cnt[species[i]], 1);
}

__global__ void offs_kernel(const int* cnt, int* offs) {
  offs[0] = 0;
  offs[1] = cnt[0];
  offs[2] = cnt[0] + cnt[1];
  offs[3] = N_ATOMS;
}

__global__ void scatter_kernel(const int* __restrict__ species, int* pos,
                               const int* __restrict__ offs, int* idx_list, int* pos_of) {
  int i = blockIdx.x * 256 + threadIdx.x;
  if (i < N_ATOMS) {
    int s = species[i];
    int p = offs[s] + atomicAdd(&pos[s], 1);
    idx_list[p] = i;
    pos_of[i] = p;
  }
}

// Transpose + bf16 convert: in f32 [S][R][C] -> out bf16 [S][C][R]
__global__ void transpose_kernel(const float* __restrict__ in, bf16* __restrict__ outp,
                                 int R, int C) {
  __shared__ float tile[64][65];
  int sp = blockIdx.z;
  const float* ins = in + (size_t)sp * R * C;
  bf16* outs = outp + (size_t)sp * R * C;
  int r0 = blockIdx.y * 64, c0 = blockIdx.x * 64;
  int tc = threadIdx.x & 63, tr4 = threadIdx.x >> 6;
#pragma unroll
  for (int it = 0; it < 16; ++it) {
    int r = it * 4 + tr4;
    tile[r][tc] = ins[(size_t)(r0 + r) * C + c0 + tc];
  }
  __syncthreads();
#pragma unroll
  for (int it = 0; it < 16; ++it) {
    int oc = it * 4 + tr4;
    outs[(size_t)(c0 + oc) * R + r0 + tc] = (bf16)tile[tc][oc];
  }
}

// ---------------- LayerNorm (writes bf16 rows in permuted order) ----------------

__global__ __launch_bounds__(256) void ln_kernel(
    const float* __restrict__ feat, const float* __restrict__ gamma,
    const float* __restrict__ beta, const int* __restrict__ species,
    const int* __restrict__ pos_of, bf16* __restrict__ xln) {
  int atom = blockIdx.x, tid = threadIdx.x;
  const float4* frow = (const float4*)(feat + (size_t)atom * F_DIM);
  float4 v0 = frow[tid];
  bool has2 = tid < 224;
  float4 v1 = has2 ? frow[256 + tid] : make_float4(0.f, 0.f, 0.f, 0.f);
  float s = v0.x + v0.y + v0.z + v0.w;
  float s2 = v0.x * v0.x + v0.y * v0.y + v0.z * v0.z + v0.w * v0.w;
  if (has2) {
    s += v1.x + v1.y + v1.z + v1.w;
    s2 += v1.x * v1.x + v1.y * v1.y + v1.z * v1.z + v1.w * v1.w;
  }
#pragma unroll
  for (int m = 1; m < 64; m <<= 1) {
    s += __shfl_xor(s, m);
    s2 += __shfl_xor(s2, m);
  }
  __shared__ float red[4][2];
  if ((tid & 63) == 0) { red[tid >> 6][0] = s; red[tid >> 6][1] = s2; }
  __syncthreads();
  s = red[0][0] + red[1][0] + red[2][0] + red[3][0];
  s2 = red[0][1] + red[1][1] + red[2][1] + red[3][1];
  float mu = s * (1.f / F_DIM);
  float var = s2 * (1.f / F_DIM) - mu * mu;
  float rsig = rsqrtf(var + 1e-5f);
  int sp = species[atom];
  size_t p = (size_t)pos_of[atom];
  const float4* g4 = (const float4*)(gamma + (size_t)sp * F_DIM);
  const float4* b4 = (const float4*)(beta + (size_t)sp * F_DIM);
  bf16* orow = xln + p * F_DIM;
  {
    float4 g = g4[tid], b = b4[tid];
    bf16x4 o;
    o[0] = (bf16)((v0.x - mu) * rsig * g.x + b.x);
    o[1] = (bf16)((v0.y - mu) * rsig * g.y + b.y);
    o[2] = (bf16)((v0.z - mu) * rsig * g.z + b.z);
    o[3] = (bf16)((v0.w - mu) * rsig * g.w + b.w);
    *(bf16x4*)(orow + 4 * tid) = o;
  }
  if (has2) {
    float4 g = g4[256 + tid], b = b4[256 + tid];
    bf16x4 o;
    o[0] = (bf16)((v1.x - mu) * rsig * g.x + b.x);
    o[1] = (bf16)((v1.y - mu) * rsig * g.y + b.y);
    o[2] = (bf16)((v1.z - mu) * rsig * g.z + b.z);
    o[3] = (bf16)((v1.w - mu) * rsig * g.w + b.w);
    *(bf16x4*)(orow + 4 * (256 + tid)) = o;
  }
}

// ---------------- bf16 MFMA GEMM, 128x128 tile, BK=64, 2-phase dbuf ----------------
// A: [rows][lda_e] bf16 (permuted, species-contiguous). BT: [S][512][K] bf16.
// EPI 0: Hout[r][c] = silu(acc + bias[c])   (h1)
// EPI 1: e_perm[r] += sum_c silu(acc + bias[c]) * w3[c]

template <int EPI>
__global__ __launch_bounds__(256, 2) void gemm_kernel(
    const bf16* __restrict__ A, int lda_e, const bf16* __restrict__ BT, int K,
    const float* __restrict__ bias, const float* __restrict__ w3,
    bf16* __restrict__ Hout, float* __restrict__ e_perm,
    const int* __restrict__ offs, int nby) {
  __shared__ char smem[2][2][16384];  // [buf][A/B][128 rows x 64 k x bf16]

  int total = 4 * nby * S_NUM;
  int lid = blockIdx.x;
  // bijective XCD-chunk swizzle (m204)
  int q = total >> 3, r = total & 7;
  int xcd = lid & 7, sl = lid >> 3;
  int w = (xcd < r ? xcd * (q + 1) : r * (q + 1) + (xcd - r) * q) + sl;
  int bx = w & 3;
  int t2 = w >> 2;
  int by = t2 % nby;
  int sp = t2 / nby;

  int rstart = offs[sp], rend = offs[sp + 1];
  int r0 = rstart + by * 128;
  if (r0 >= rend) return;

  int tid = threadIdx.x;
  int lane = tid & 63, wid = tid >> 6;
  int wm = wid >> 1, wn = wid & 1;
  int n0 = bx * 128;

  const char* Ag = (const char*)A;
  size_t ldab = (size_t)lda_e * 2;
  const char* Bg = (const char*)(BT + (size_t)sp * H_DIM * K);
  size_t ldbb = (size_t)K * 2;

  int l8 = lane >> 3;
  int sw_st = (((lane & 7) ^ l8) << 4);  // inverse-swizzled source byte (involution)

  auto stage = [&](int buf, int kt) {
    int k0b = kt * 128;  // kt*64 elems * 2B
#pragma unroll
    for (int t = 0; t < 4; ++t) {
      int chunk = t * 4 + wid;       // 0..15, wave-uniform
      int row = chunk * 8 + l8;      // 0..127 (per-lane)
      int ar = r0 + row;
      if (ar > rend - 1) ar = rend - 1;
      gload_lds16(Ag + (size_t)ar * ldab + k0b + sw_st, &smem[buf][0][chunk * 1024]);
      gload_lds16(Bg + (size_t)(n0 + row) * ldbb + k0b + sw_st, &smem[buf][1][chunk * 1024]);
    }
  };

  f32x4 acc[4][4];
#pragma unroll
  for (int a_ = 0; a_ < 4; ++a_)
#pragma unroll
    for (int b_ = 0; b_ < 4; ++b_) {
      f32x4 z = {0.f, 0.f, 0.f, 0.f};
      acc[a_][b_] = z;
    }

  int lr = lane & 15, lg = lane >> 4;
  int swr = (lr & 7) << 4;

  auto compute = [&](int buf) {
    const char* Ab = smem[buf][0];
    const char* Bb = smem[buf][1];
#pragma unroll
    for (int kh = 0; kh < 2; ++kh) {
      int off = (kh * 64 + lg * 16) ^ swr;
      bf16x8 av[4], bv[4];
#pragma unroll
      for (int fm = 0; fm < 4; ++fm) {
        int row = wm * 64 + fm * 16 + lr;
        av[fm] = *(const bf16x8*)(Ab + row * 128 + off);
      }
#pragma unroll
      for (int fn = 0; fn < 4; ++fn) {
        int row = wn * 64 + fn * 16 + lr;
        bv[fn] = *(const bf16x8*)(Bb + row * 128 + off);
      }
#pragma unroll
      for (int fm = 0; fm < 4; ++fm)
#pragma unroll
        for (int fn = 0; fn < 4; ++fn)
          acc[fm][fn] =
              __builtin_amdgcn_mfma_f32_16x16x32_bf16(av[fm], bv[fn], acc[fm][fn], 0, 0, 0);
    }
  };

  int NT = K / 64;
  stage(0, 0);
  __syncthreads();
  int cur = 0;
#pragma unroll 1
  for (int t = 0; t < NT; ++t) {
    if (t + 1 < NT) stage(cur ^ 1, t + 1);
    compute(cur);
    __syncthreads();
    cur ^= 1;
  }

  const float* bs = bias + sp * H_DIM;
  if (EPI == 0) {
#pragma unroll
    for (int fm = 0; fm < 4; ++fm)
#pragma unroll
      for (int i = 0; i < 4; ++i) {
        int rr = r0 + wm * 64 + fm * 16 + lg * 4 + i;
        if (rr < rend) {
#pragma unroll
          for (int fn = 0; fn < 4; ++fn) {
            int c = n0 + wn * 64 + fn * 16 + lr;
            float x = acc[fm][fn][i] + bs[c];
            float h = x / (1.f + __expf(-x));
            Hout[(size_t)rr * H_DIM + c] = (bf16)h;
          }
        }
      }
  } else {
    const float* ws3 = w3 + sp * H_DIM;
#pragma unroll
    for (int fm = 0; fm < 4; ++fm)
#pragma unroll
      for (int i = 0; i < 4; ++i) {
        int rr = r0 + wm * 64 + fm * 16 + lg * 4 + i;
        float part = 0.f;
#pragma unroll
        for (int fn = 0; fn < 4; ++fn) {
          int c = n0 + wn * 64 + fn * 16 + lr;
          float x = acc[fm][fn][i] + bs[c];
          part += (x / (1.f + __expf(-x))) * ws3[c];
        }
        part += __shfl_xor(part, 1);
        part += __shfl_xor(part, 2);
        part += __shfl_xor(part, 4);
        part += __shfl_xor(part, 8);
        if (lr == 0 && rr < rend) atomicAdd(&e_perm[rr], part);
      }
  }
}

// ---------------- finalize: + b3 + comp_w, segment-sum ----------------

__global__ void finalize_kernel(const float* __restrict__ e_perm, const int* __restrict__ offs,
                                const float* __restrict__ b3, const float* __restrict__ comp_w,
                                const int* __restrict__ idx_list,
                                const int* __restrict__ struct_id, float* out) {
  int rr = blockIdx.x * 256 + threadIdx.x;
  if (rr >= N_ATOMS) return;
  int s = (rr >= offs[1]) + (rr >= offs[2]);
  float e = e_perm[rr] + b3[s] + comp_w[s];
  atomicAdd(&out[struct_id[idx_list[rr]]], e);
}

// ---------------- launch ----------------

extern "C" void kernel_launch(void* const* d_in, const int* in_sizes, int n_in,
                              void* d_out, int out_size, void* d_ws, size_t ws_size,
                              hipStream_t stream) {
  const float* features = (const float*)d_in[0];
  const float* ln_gamma = (const float*)d_in[1];
  const float* ln_beta = (const float*)d_in[2];
  const float* W1 = (const float*)d_in[3];
  const float* b1 = (const float*)d_in[4];
  const float* W2 = (const float*)d_in[5];
  const float* b2 = (const float*)d_in[6];
  const float* w3 = (const float*)d_in[7];
  const float* b3 = (const float*)d_in[8];
  const float* comp_w = (const float*)d_in[9];
  const int* species = (const int*)d_in[10];
  const int* struct_id = (const int*)d_in[11];
  float* out = (float*)d_out;

  char* ws = (char*)d_ws;
  size_t off = 0;
  auto alloc = [&](size_t bytes) {
    char* p = ws + off;
    off += (bytes + 255) & ~(size_t)255;
    return p;
  };
  bf16* W1T = (bf16*)alloc((size_t)S_NUM * H_DIM * F_DIM * 2);
  bf16* W2T = (bf16*)alloc((size_t)S_NUM * H_DIM * H_DIM * 2);
  bf16* xln = (bf16*)alloc((size_t)N_ATOMS * F_DIM * 2);
  bf16* h1 = (bf16*)alloc((size_t)N_ATOMS * H_DIM * 2);
  float* e_perm = (float*)alloc((size_t)N_ATOMS * 4);
  int* idx_list = (int*)alloc((size_t)N_ATOMS * 4);
  int* pos_of = (int*)alloc((size_t)N_ATOMS * 4);
  int* ints = (int*)alloc(64);
  int* cnt = ints;
  int* pos = ints + 3;
  int* offs = ints + 6;

  int nb = (N_ATOMS + 255) / 256;
  init_kernel<<<nb, 256, 0, stream>>>(e_perm, out, ints);
  count_kernel<<<nb, 256, 0, stream>>>(species, cnt);
  offs_kernel<<<1, 1, 0, stream>>>(cnt, offs);
  scatter_kernel<<<nb, 256, 0, stream>>>(species, pos, offs, idx_list, pos_of);
  transpose_kernel<<<dim3(H_DIM / 64, F_DIM / 64, S_NUM), 256, 0, stream>>>(W1, W1T, F_DIM, H_DIM);
  transpose_kernel<<<dim3(H_DIM / 64, H_DIM / 64, S_NUM), 256, 0, stream>>>(W2, W2T, H_DIM, H_DIM);
  ln_kernel<<<N_ATOMS, 256, 0, stream>>>(features, ln_gamma, ln_beta, species, pos_of, xln);

  int nby = (N_ATOMS + 127) / 128;  // 157
  gemm_kernel<0><<<4 * nby * S_NUM, 256, 0, stream>>>(xln, F_DIM, W1T, F_DIM, b1, nullptr, h1,
                                                      nullptr, offs, nby);
  gemm_kernel<1><<<4 * nby * S_NUM, 256, 0, stream>>>(h1, H_DIM, W2T, H_DIM, b2, w3, nullptr,
                                                      e_perm, offs, nby);
  finalize_kernel<<<nb, 256, 0, stream>>>(e_perm, offs, b3, comp_w, idx_list, struct_id, out);
}

// Round 2
// 248.460 us; speedup vs baseline: 2.2725x; 2.2725x over previous
//
#include <hip/hip_runtime.h>
#include <cstdint>
#include <cstddef>

#define N_ATOMS 20000
#define F_DIM 1920
#define H_DIM 512
#define S_NUM 3
#define NSTRUCT_ 16

typedef __bf16 bf16;
typedef __bf16 bf16x4 __attribute__((ext_vector_type(4)));
typedef __bf16 bf16x8 __attribute__((ext_vector_type(8)));
typedef float f32x4 __attribute__((ext_vector_type(4)));

__device__ __forceinline__ void gload_lds16(const void* g, void* l) {
  __builtin_amdgcn_global_load_lds(
      (const __attribute__((address_space(1))) unsigned int*)g,
      (__attribute__((address_space(3))) unsigned int*)l, 16, 0, 0);
}

// ---------------- routing / setup kernels ----------------

__global__ void init_kernel(float* e_perm, float* out, int* ints) {
  int i = blockIdx.x * 256 + threadIdx.x;
  if (i < N_ATOMS) e_perm[i] = 0.f;
  if (i < NSTRUCT_) out[i] = 0.f;
  if (i < 6) ints[i] = 0;  // cnt[0..2], pos[0..2]
}

// Wave-aggregated species histogram: 3 atomics per wave instead of 1 per thread.
__global__ void count_kernel(const int* __restrict__ species, int* cnt) {
  int i = blockIdx.x * 256 + threadIdx.x;
  int lane = threadIdx.x & 63;
  int sp = (i < N_ATOMS) ? species[i] : -1;
#pragma unroll
  for (int s = 0; s < S_NUM; ++s) {
    unsigned long long mask = __ballot(sp == s);
    if (mask && lane == (__ffsll((long long)mask) - 1))
      atomicAdd(&cnt[s], __popcll(mask));
  }
}

__global__ void offs_kernel(const int* cnt, int* offs) {
  offs[0] = 0;
  offs[1] = cnt[0];
  offs[2] = cnt[0] + cnt[1];
  offs[3] = N_ATOMS;
}

// Wave-aggregated scatter: one atomicAdd per wave per species; lane rank via
// ballot-prefix popcount. Any within-species order is valid (pos_of maps back).
__global__ void scatter_kernel(const int* __restrict__ species, int* pos,
                               const int* __restrict__ offs, int* idx_list, int* pos_of) {
  int i = blockIdx.x * 256 + threadIdx.x;
  int lane = threadIdx.x & 63;
  int sp = (i < N_ATOMS) ? species[i] : -1;
#pragma unroll
  for (int s = 0; s < S_NUM; ++s) {
    unsigned long long mask = __ballot(sp == s);
    if (!mask) continue;
    int leader = __ffsll((long long)mask) - 1;
    int base = 0;
    if (lane == leader) base = atomicAdd(&pos[s], __popcll(mask));
    base = __shfl(base, leader);
    if (sp == s) {
      int rank = __popcll(mask & ((1ULL << lane) - 1ULL));
      int p = offs[s] + base + rank;
      idx_list[p] = i;
      pos_of[i] = p;
    }
  }
}

// Transpose + bf16 convert: in f32 [S][R][C] -> out bf16 [S][C][R]
__global__ void transpose_kernel(const float* __restrict__ in, bf16* __restrict__ outp,
                                 int R, int C) {
  __shared__ float tile[64][65];
  int sp = blockIdx.z;
  const float* ins = in + (size_t)sp * R * C;
  bf16* outs = outp + (size_t)sp * R * C;
  int r0 = blockIdx.y * 64, c0 = blockIdx.x * 64;
  int tc = threadIdx.x & 63, tr4 = threadIdx.x >> 6;
#pragma unroll
  for (int it = 0; it < 16; ++it) {
    int r = it * 4 + tr4;
    tile[r][tc] = ins[(size_t)(r0 + r) * C + c0 + tc];
  }
  __syncthreads();
#pragma unroll
  for (int it = 0; it < 16; ++it) {
    int oc = it * 4 + tr4;
    outs[(size_t)(c0 + oc) * R + r0 + tc] = (bf16)tile[tc][oc];
  }
}

// ---------------- LayerNorm (writes bf16 rows in permuted order) ----------------

__global__ __launch_bounds__(256) void ln_kernel(
    const float* __restrict__ feat, const float* __restrict__ gamma,
    const float* __restrict__ beta, const int* __restrict__ species,
    const int* __restrict__ pos_of, bf16* __restrict__ xln) {
  int atom = blockIdx.x, tid = threadIdx.x;
  const float4* frow = (const float4*)(feat + (size_t)atom * F_DIM);
  float4 v0 = frow[tid];
  bool has2 = tid < 224;
  float4 v1 = has2 ? frow[256 + tid] : make_float4(0.f, 0.f, 0.f, 0.f);
  float s = v0.x + v0.y + v0.z + v0.w;
  float s2 = v0.x * v0.x + v0.y * v0.y + v0.z * v0.z + v0.w * v0.w;
  if (has2) {
    s += v1.x + v1.y + v1.z + v1.w;
    s2 += v1.x * v1.x + v1.y * v1.y + v1.z * v1.z + v1.w * v1.w;
  }
#pragma unroll
  for (int m = 1; m < 64; m <<= 1) {
    s += __shfl_xor(s, m);
    s2 += __shfl_xor(s2, m);
  }
  __shared__ float red[4][2];
  if ((tid & 63) == 0) { red[tid >> 6][0] = s; red[tid >> 6][1] = s2; }
  __syncthreads();
  s = red[0][0] + red[1][0] + red[2][0] + red[3][0];
  s2 = red[0][1] + red[1][1] + red[2][1] + red[3][1];
  float mu = s * (1.f / F_DIM);
  float var = s2 * (1.f / F_DIM) - mu * mu;
  float rsig = rsqrtf(var + 1e-5f);
  int sp = species[atom];
  size_t p = (size_t)pos_of[atom];
  const float4* g4 = (const float4*)(gamma + (size_t)sp * F_DIM);
  const float4* b4 = (const float4*)(beta + (size_t)sp * F_DIM);
  bf16* orow = xln + p * F_DIM;
  {
    float4 g = g4[tid], b = b4[tid];
    bf16x4 o;
    o[0] = (bf16)((v0.x - mu) * rsig * g.x + b.x);
    o[1] = (bf16)((v0.y - mu) * rsig * g.y + b.y);
    o[2] = (bf16)((v0.z - mu) * rsig * g.z + b.z);
    o[3] = (bf16)((v0.w - mu) * rsig * g.w + b.w);
    *(bf16x4*)(orow + 4 * tid) = o;
  }
  if (has2) {
    float4 g = g4[256 + tid], b = b4[256 + tid];
    bf16x4 o;
    o[0] = (bf16)((v1.x - mu) * rsig * g.x + b.x);
    o[1] = (bf16)((v1.y - mu) * rsig * g.y + b.y);
    o[2] = (bf16)((v1.z - mu) * rsig * g.z + b.z);
    o[3] = (bf16)((v1.w - mu) * rsig * g.w + b.w);
    *(bf16x4*)(orow + 4 * (256 + tid)) = o;
  }
}

// ---------------- bf16 MFMA GEMM, 128x128 tile, BK=64, 2-phase dbuf ----------------
// A: [rows][lda_e] bf16 (permuted, species-contiguous). BT: [S][512][K] bf16.
// EPI 0: Hout[r][c] = silu(acc + bias[c])   (h1)
// EPI 1: e_perm[r] += sum_c silu(acc + bias[c]) * w3[c]

template <int EPI>
__global__ __launch_bounds__(256, 2) void gemm_kernel(
    const bf16* __restrict__ A, int lda_e, const bf16* __restrict__ BT, int K,
    const float* __restrict__ bias, const float* __restrict__ w3,
    bf16* __restrict__ Hout, float* __restrict__ e_perm,
    const int* __restrict__ offs, int nby) {
  __shared__ char smem[2][2][16384];  // [buf][A/B][128 rows x 64 k x bf16]

  int total = 4 * nby * S_NUM;
  int lid = blockIdx.x;
  // bijective XCD-chunk swizzle (m204)
  int q = total >> 3, r = total & 7;
  int xcd = lid & 7, sl = lid >> 3;
  int w = (xcd < r ? xcd * (q + 1) : r * (q + 1) + (xcd - r) * q) + sl;
  int bx = w & 3;
  int t2 = w >> 2;
  int by = t2 % nby;
  int sp = t2 / nby;

  int rstart = offs[sp], rend = offs[sp + 1];
  int r0 = rstart + by * 128;
  if (r0 >= rend) return;

  int tid = threadIdx.x;
  int lane = tid & 63, wid = tid >> 6;
  int wm = wid >> 1, wn = wid & 1;
  int n0 = bx * 128;

  const char* Ag = (const char*)A;
  size_t ldab = (size_t)lda_e * 2;
  const char* Bg = (const char*)(BT + (size_t)sp * H_DIM * K);
  size_t ldbb = (size_t)K * 2;

  int l8 = lane >> 3;
  int sw_st = (((lane & 7) ^ l8) << 4);  // inverse-swizzled source byte (involution)

  auto stage = [&](int buf, int kt) {
    int k0b = kt * 128;  // kt*64 elems * 2B
#pragma unroll
    for (int t = 0; t < 4; ++t) {
      int chunk = t * 4 + wid;       // 0..15, wave-uniform
      int row = chunk * 8 + l8;      // 0..127 (per-lane)
      int ar = r0 + row;
      if (ar > rend - 1) ar = rend - 1;
      gload_lds16(Ag + (size_t)ar * ldab + k0b + sw_st, &smem[buf][0][chunk * 1024]);
      gload_lds16(Bg + (size_t)(n0 + row) * ldbb + k0b + sw_st, &smem[buf][1][chunk * 1024]);
    }
  };

  f32x4 acc[4][4];
#pragma unroll
  for (int a_ = 0; a_ < 4; ++a_)
#pragma unroll
    for (int b_ = 0; b_ < 4; ++b_) {
      f32x4 z = {0.f, 0.f, 0.f, 0.f};
      acc[a_][b_] = z;
    }

  int lr = lane & 15, lg = lane >> 4;
  int swr = (lr & 7) << 4;

  auto compute = [&](int buf) {
    const char* Ab = smem[buf][0];
    const char* Bb = smem[buf][1];
#pragma unroll
    for (int kh = 0; kh < 2; ++kh) {
      int off = (kh * 64 + lg * 16) ^ swr;
      bf16x8 av[4], bv[4];
#pragma unroll
      for (int fm = 0; fm < 4; ++fm) {
        int row = wm * 64 + fm * 16 + lr;
        av[fm] = *(const bf16x8*)(Ab + row * 128 + off);
      }
#pragma unroll
      for (int fn = 0; fn < 4; ++fn) {
        int row = wn * 64 + fn * 16 + lr;
        bv[fn] = *(const bf16x8*)(Bb + row * 128 + off);
      }
#pragma unroll
      for (int fm = 0; fm < 4; ++fm)
#pragma unroll
        for (int fn = 0; fn < 4; ++fn)
          acc[fm][fn] =
              __builtin_amdgcn_mfma_f32_16x16x32_bf16(av[fm], bv[fn], acc[fm][fn], 0, 0, 0);
    }
  };

  int NT = K / 64;
  stage(0, 0);
  __syncthreads();
  int cur = 0;
#pragma unroll 1
  for (int t = 0; t < NT; ++t) {
    if (t + 1 < NT) stage(cur ^ 1, t + 1);
    compute(cur);
    __syncthreads();
    cur ^= 1;
  }

  const float* bs = bias + sp * H_DIM;
  if (EPI == 0) {
#pragma unroll
    for (int fm = 0; fm < 4; ++fm)
#pragma unroll
      for (int i = 0; i < 4; ++i) {
        int rr = r0 + wm * 64 + fm * 16 + lg * 4 + i;
        if (rr < rend) {
#pragma unroll
          for (int fn = 0; fn < 4; ++fn) {
            int c = n0 + wn * 64 + fn * 16 + lr;
            float x = acc[fm][fn][i] + bs[c];
            float h = x / (1.f + __expf(-x));
            Hout[(size_t)rr * H_DIM + c] = (bf16)h;
          }
        }
      }
  } else {
    const float* ws3 = w3 + sp * H_DIM;
#pragma unroll
    for (int fm = 0; fm < 4; ++fm)
#pragma unroll
      for (int i = 0; i < 4; ++i) {
        int rr = r0 + wm * 64 + fm * 16 + lg * 4 + i;
        float part = 0.f;
#pragma unroll
        for (int fn = 0; fn < 4; ++fn) {
          int c = n0 + wn * 64 + fn * 16 + lr;
          float x = acc[fm][fn][i] + bs[c];
          part += (x / (1.f + __expf(-x))) * ws3[c];
        }
        part += __shfl_xor(part, 1);
        part += __shfl_xor(part, 2);
        part += __shfl_xor(part, 4);
        part += __shfl_xor(part, 8);
        if (lr == 0 && rr < rend) atomicAdd(&e_perm[rr], part);
      }
  }
}

// ---------------- finalize: + b3 + comp_w, segment-sum (block-local bins) ----------------

__global__ void finalize_kernel(const float* __restrict__ e_perm, const int* __restrict__ offs,
                                const float* __restrict__ b3, const float* __restrict__ comp_w,
                                const int* __restrict__ idx_list,
                                const int* __restrict__ struct_id, float* out) {
  __shared__ float bins[NSTRUCT_];
  if (threadIdx.x < NSTRUCT_) bins[threadIdx.x] = 0.f;
  __syncthreads();
  int rr = blockIdx.x * 256 + threadIdx.x;
  if (rr < N_ATOMS) {
    int s = (rr >= offs[1]) + (rr >= offs[2]);
    float e = e_perm[rr] + b3[s] + comp_w[s];
    atomicAdd(&bins[struct_id[idx_list[rr]]], e);
  }
  __syncthreads();
  if (threadIdx.x < NSTRUCT_) atomicAdd(&out[threadIdx.x], bins[threadIdx.x]);
}

// ---------------- launch ----------------

extern "C" void kernel_launch(void* const* d_in, const int* in_sizes, int n_in,
                              void* d_out, int out_size, void* d_ws, size_t ws_size,
                              hipStream_t stream) {
  const float* features = (const float*)d_in[0];
  const float* ln_gamma = (const float*)d_in[1];
  const float* ln_beta = (const float*)d_in[2];
  const float* W1 = (const float*)d_in[3];
  const float* b1 = (const float*)d_in[4];
  const float* W2 = (const float*)d_in[5];
  const float* b2 = (const float*)d_in[6];
  const float* w3 = (const float*)d_in[7];
  const float* b3 = (const float*)d_in[8];
  const float* comp_w = (const float*)d_in[9];
  const int* species = (const int*)d_in[10];
  const int* struct_id = (const int*)d_in[11];
  float* out = (float*)d_out;

  char* ws = (char*)d_ws;
  size_t off = 0;
  auto alloc = [&](size_t bytes) {
    char* p = ws + off;
    off += (bytes + 255) & ~(size_t)255;
    return p;
  };
  bf16* W1T = (bf16*)alloc((size_t)S_NUM * H_DIM * F_DIM * 2);
  bf16* W2T = (bf16*)alloc((size_t)S_NUM * H_DIM * H_DIM * 2);
  bf16* xln = (bf16*)alloc((size_t)N_ATOMS * F_DIM * 2);
  bf16* h1 = (bf16*)alloc((size_t)N_ATOMS * H_DIM * 2);
  float* e_perm = (float*)alloc((size_t)N_ATOMS * 4);
  int* idx_list = (int*)alloc((size_t)N_ATOMS * 4);
  int* pos_of = (int*)alloc((size_t)N_ATOMS * 4);
  int* ints = (int*)alloc(64);
  int* cnt = ints;
  int* pos = ints + 3;
  int* offs = ints + 6;

  int nb = (N_ATOMS + 255) / 256;
  init_kernel<<<nb, 256, 0, stream>>>(e_perm, out, ints);
  count_kernel<<<nb, 256, 0, stream>>>(species, cnt);
  offs_kernel<<<1, 1, 0, stream>>>(cnt, offs);
  scatter_kernel<<<nb, 256, 0, stream>>>(species, pos, offs, idx_list, pos_of);
  transpose_kernel<<<dim3(H_DIM / 64, F_DIM / 64, S_NUM), 256, 0, stream>>>(W1, W1T, F_DIM, H_DIM);
  transpose_kernel<<<dim3(H_DIM / 64, H_DIM / 64, S_NUM), 256, 0, stream>>>(W2, W2T, H_DIM, H_DIM);
  ln_kernel<<<N_ATOMS, 256, 0, stream>>>(features, ln_gamma, ln_beta, species, pos_of, xln);

  int nby = (N_ATOMS + 127) / 128;  // 157
  gemm_kernel<0><<<4 * nby * S_NUM, 256, 0, stream>>>(xln, F_DIM, W1T, F_DIM, b1, nullptr, h1,
                                                      nullptr, offs, nby);
  gemm_kernel<1><<<4 * nby * S_NUM, 256, 0, stream>>>(h1, H_DIM, W2T, H_DIM, b2, w3, nullptr,
                                                      e_perm, offs, nby);
  finalize_kernel<<<nb, 256, 0, stream>>>(e_perm, offs, b3, comp_w, idx_list, struct_id, out);
}

// Round 3
// 222.304 us; speedup vs baseline: 2.5399x; 1.1177x over previous
//
#include <hip/hip_runtime.h>
#include <cstdint>
#include <cstddef>

#define N_ATOMS 20000
#define F_DIM 1920
#define H_DIM 512
#define S_NUM 3
#define NSTRUCT_ 16

typedef __bf16 bf16;
typedef __bf16 bf16x4 __attribute__((ext_vector_type(4)));
typedef __bf16 bf16x8 __attribute__((ext_vector_type(8)));
typedef float f32x4 __attribute__((ext_vector_type(4)));

__device__ __forceinline__ void gload_lds16(const void* g, void* l) {
  __builtin_amdgcn_global_load_lds(
      (const __attribute__((address_space(1))) unsigned int*)g,
      (__attribute__((address_space(3))) unsigned int*)l, 16, 0, 0);
}

// ---------------- routing / setup kernels ----------------

__global__ void init_kernel(float* e_perm, float* out, int* ints) {
  int i = blockIdx.x * 256 + threadIdx.x;
  if (i < N_ATOMS) e_perm[i] = 0.f;
  if (i < NSTRUCT_) out[i] = 0.f;
  if (i < 6) ints[i] = 0;  // cnt[0..2], pos[0..2]
}

// Wave-aggregated species histogram: 3 atomics per wave instead of 1 per thread.
__global__ void count_kernel(const int* __restrict__ species, int* cnt) {
  int i = blockIdx.x * 256 + threadIdx.x;
  int lane = threadIdx.x & 63;
  int sp = (i < N_ATOMS) ? species[i] : -1;
#pragma unroll
  for (int s = 0; s < S_NUM; ++s) {
    unsigned long long mask = __ballot(sp == s);
    if (mask && lane == (__ffsll((long long)mask) - 1))
      atomicAdd(&cnt[s], __popcll(mask));
  }
}

__global__ void offs_kernel(const int* cnt, int* offs) {
  offs[0] = 0;
  offs[1] = cnt[0];
  offs[2] = cnt[0] + cnt[1];
  offs[3] = N_ATOMS;
}

// Wave-aggregated scatter: one atomicAdd per wave per species; lane rank via
// ballot-prefix popcount. Any within-species order is valid (pos_of maps back).
__global__ void scatter_kernel(const int* __restrict__ species, int* pos,
                               const int* __restrict__ offs, int* idx_list, int* pos_of) {
  int i = blockIdx.x * 256 + threadIdx.x;
  int lane = threadIdx.x & 63;
  int sp = (i < N_ATOMS) ? species[i] : -1;
#pragma unroll
  for (int s = 0; s < S_NUM; ++s) {
    unsigned long long mask = __ballot(sp == s);
    if (!mask) continue;
    int leader = __ffsll((long long)mask) - 1;
    int base = 0;
    if (lane == leader) base = atomicAdd(&pos[s], __popcll(mask));
    base = __shfl(base, leader);
    if (sp == s) {
      int rank = __popcll(mask & ((1ULL << lane) - 1ULL));
      int p = offs[s] + base + rank;
      idx_list[p] = i;
      pos_of[i] = p;
    }
  }
}

// Transpose + bf16 convert: in f32 [S][R][C] -> out bf16 [S][C][R]
__global__ void transpose_kernel(const float* __restrict__ in, bf16* __restrict__ outp,
                                 int R, int C) {
  __shared__ float tile[64][65];
  int sp = blockIdx.z;
  const float* ins = in + (size_t)sp * R * C;
  bf16* outs = outp + (size_t)sp * R * C;
  int r0 = blockIdx.y * 64, c0 = blockIdx.x * 64;
  int tc = threadIdx.x & 63, tr4 = threadIdx.x >> 6;
#pragma unroll
  for (int it = 0; it < 16; ++it) {
    int r = it * 4 + tr4;
    tile[r][tc] = ins[(size_t)(r0 + r) * C + c0 + tc];
  }
  __syncthreads();
#pragma unroll
  for (int it = 0; it < 16; ++it) {
    int oc = it * 4 + tr4;
    outs[(size_t)(c0 + oc) * R + r0 + tc] = (bf16)tile[tc][oc];
  }
}

// ---------------- LayerNorm (writes bf16 rows in permuted order) ----------------

__global__ __launch_bounds__(256) void ln_kernel(
    const float* __restrict__ feat, const float* __restrict__ gamma,
    const float* __restrict__ beta, const int* __restrict__ species,
    const int* __restrict__ pos_of, bf16* __restrict__ xln) {
  int atom = blockIdx.x, tid = threadIdx.x;
  const float4* frow = (const float4*)(feat + (size_t)atom * F_DIM);
  float4 v0 = frow[tid];
  bool has2 = tid < 224;
  float4 v1 = has2 ? frow[256 + tid] : make_float4(0.f, 0.f, 0.f, 0.f);
  float s = v0.x + v0.y + v0.z + v0.w;
  float s2 = v0.x * v0.x + v0.y * v0.y + v0.z * v0.z + v0.w * v0.w;
  if (has2) {
    s += v1.x + v1.y + v1.z + v1.w;
    s2 += v1.x * v1.x + v1.y * v1.y + v1.z * v1.z + v1.w * v1.w;
  }
#pragma unroll
  for (int m = 1; m < 64; m <<= 1) {
    s += __shfl_xor(s, m);
    s2 += __shfl_xor(s2, m);
  }
  __shared__ float red[4][2];
  if ((tid & 63) == 0) { red[tid >> 6][0] = s; red[tid >> 6][1] = s2; }
  __syncthreads();
  s = red[0][0] + red[1][0] + red[2][0] + red[3][0];
  s2 = red[0][1] + red[1][1] + red[2][1] + red[3][1];
  float mu = s * (1.f / F_DIM);
  float var = s2 * (1.f / F_DIM) - mu * mu;
  float rsig = rsqrtf(var + 1e-5f);
  int sp = species[atom];
  size_t p = (size_t)pos_of[atom];
  const float4* g4 = (const float4*)(gamma + (size_t)sp * F_DIM);
  const float4* b4 = (const float4*)(beta + (size_t)sp * F_DIM);
  bf16* orow = xln + p * F_DIM;
  {
    float4 g = g4[tid], b = b4[tid];
    bf16x4 o;
    o[0] = (bf16)((v0.x - mu) * rsig * g.x + b.x);
    o[1] = (bf16)((v0.y - mu) * rsig * g.y + b.y);
    o[2] = (bf16)((v0.z - mu) * rsig * g.z + b.z);
    o[3] = (bf16)((v0.w - mu) * rsig * g.w + b.w);
    *(bf16x4*)(orow + 4 * tid) = o;
  }
  if (has2) {
    float4 g = g4[256 + tid], b = b4[256 + tid];
    bf16x4 o;
    o[0] = (bf16)((v1.x - mu) * rsig * g.x + b.x);
    o[1] = (bf16)((v1.y - mu) * rsig * g.y + b.y);
    o[2] = (bf16)((v1.z - mu) * rsig * g.z + b.z);
    o[3] = (bf16)((v1.w - mu) * rsig * g.w + b.w);
    *(bf16x4*)(orow + 4 * (256 + tid)) = o;
  }
}

// ---------------- bf16 MFMA GEMM, 128x128 tile, BK=64, single-buffer 32KB ----------
// m97 structure: stage -> barrier -> compute -> barrier. 32KB LDS allows ~5
// blocks/CU (was 2 with 64KB dbuf, the m132 occupancy cliff).
// A: [rows][lda_e] bf16 (permuted, species-contiguous). BT: [S][512][K] bf16.
// EPI 0: Hout[r][c] = silu(acc + bias[c])   (h1)
// EPI 1: e_perm[r] += sum_c silu(acc + bias[c]) * w3[c]

template <int EPI>
__global__ __launch_bounds__(256, 4) void gemm_kernel(
    const bf16* __restrict__ A, int lda_e, const bf16* __restrict__ BT, int K,
    const float* __restrict__ bias, const float* __restrict__ w3,
    bf16* __restrict__ Hout, float* __restrict__ e_perm,
    const int* __restrict__ offs, int nby) {
  __shared__ char smem[2][16384];  // [A/B][128 rows x 64 k x bf16], single buffer

  int total = 4 * nby * S_NUM;
  int lid = blockIdx.x;
  // bijective XCD-chunk swizzle (m204)
  int q = total >> 3, r = total & 7;
  int xcd = lid & 7, sl = lid >> 3;
  int w = (xcd < r ? xcd * (q + 1) : r * (q + 1) + (xcd - r) * q) + sl;
  int bx = w & 3;
  int t2 = w >> 2;
  int by = t2 % nby;
  int sp = t2 / nby;

  int rstart = offs[sp], rend = offs[sp + 1];
  int r0 = rstart + by * 128;
  if (r0 >= rend) return;

  int tid = threadIdx.x;
  int lane = tid & 63, wid = tid >> 6;
  int wm = wid >> 1, wn = wid & 1;
  int n0 = bx * 128;

  const char* Ag = (const char*)A;
  size_t ldab = (size_t)lda_e * 2;
  const char* Bg = (const char*)(BT + (size_t)sp * H_DIM * K);
  size_t ldbb = (size_t)K * 2;

  int l8 = lane >> 3;
  int sw_st = (((lane & 7) ^ l8) << 4);  // inverse-swizzled source byte (involution)

  auto stage = [&](int kt) {
    int k0b = kt * 128;  // kt*64 elems * 2B
#pragma unroll
    for (int t = 0; t < 4; ++t) {
      int chunk = t * 4 + wid;       // 0..15, wave-uniform
      int row = chunk * 8 + l8;      // 0..127 (per-lane)
      int ar = r0 + row;
      if (ar > rend - 1) ar = rend - 1;
      gload_lds16(Ag + (size_t)ar * ldab + k0b + sw_st, &smem[0][chunk * 1024]);
      gload_lds16(Bg + (size_t)(n0 + row) * ldbb + k0b + sw_st, &smem[1][chunk * 1024]);
    }
  };

  f32x4 acc[4][4];
#pragma unroll
  for (int a_ = 0; a_ < 4; ++a_)
#pragma unroll
    for (int b_ = 0; b_ < 4; ++b_) {
      f32x4 z = {0.f, 0.f, 0.f, 0.f};
      acc[a_][b_] = z;
    }

  int lr = lane & 15, lg = lane >> 4;
  int swr = (lr & 7) << 4;

  auto compute = [&]() {
    const char* Ab = smem[0];
    const char* Bb = smem[1];
#pragma unroll
    for (int kh = 0; kh < 2; ++kh) {
      int off = (kh * 64 + lg * 16) ^ swr;
      bf16x8 av[4], bv[4];
#pragma unroll
      for (int fm = 0; fm < 4; ++fm) {
        int row = wm * 64 + fm * 16 + lr;
        av[fm] = *(const bf16x8*)(Ab + row * 128 + off);
      }
#pragma unroll
      for (int fn = 0; fn < 4; ++fn) {
        int row = wn * 64 + fn * 16 + lr;
        bv[fn] = *(const bf16x8*)(Bb + row * 128 + off);
      }
#pragma unroll
      for (int fm = 0; fm < 4; ++fm)
#pragma unroll
        for (int fn = 0; fn < 4; ++fn)
          acc[fm][fn] =
              __builtin_amdgcn_mfma_f32_16x16x32_bf16(av[fm], bv[fn], acc[fm][fn], 0, 0, 0);
    }
  };

  int NT = K / 64;
#pragma unroll 1
  for (int t = 0; t < NT; ++t) {
    stage(t);
    __syncthreads();
    compute();
    __syncthreads();
  }

  const float* bs = bias + sp * H_DIM;
  if (EPI == 0) {
#pragma unroll
    for (int fm = 0; fm < 4; ++fm)
#pragma unroll
      for (int i = 0; i < 4; ++i) {
        int rr = r0 + wm * 64 + fm * 16 + lg * 4 + i;
        if (rr < rend) {
#pragma unroll
          for (int fn = 0; fn < 4; ++fn) {
            int c = n0 + wn * 64 + fn * 16 + lr;
            float x = acc[fm][fn][i] + bs[c];
            float h = x / (1.f + __expf(-x));
            Hout[(size_t)rr * H_DIM + c] = (bf16)h;
          }
        }
      }
  } else {
    const float* ws3 = w3 + sp * H_DIM;
#pragma unroll
    for (int fm = 0; fm < 4; ++fm)
#pragma unroll
      for (int i = 0; i < 4; ++i) {
        int rr = r0 + wm * 64 + fm * 16 + lg * 4 + i;
        float part = 0.f;
#pragma unroll
        for (int fn = 0; fn < 4; ++fn) {
          int c = n0 + wn * 64 + fn * 16 + lr;
          float x = acc[fm][fn][i] + bs[c];
          part += (x / (1.f + __expf(-x))) * ws3[c];
        }
        part += __shfl_xor(part, 1);
        part += __shfl_xor(part, 2);
        part += __shfl_xor(part, 4);
        part += __shfl_xor(part, 8);
        if (lr == 0 && rr < rend) atomicAdd(&e_perm[rr], part);
      }
  }
}

// ---------------- finalize: + b3 + comp_w, segment-sum (block-local bins) ----------------

__global__ void finalize_kernel(const float* __restrict__ e_perm, const int* __restrict__ offs,
                                const float* __restrict__ b3, const float* __restrict__ comp_w,
                                const int* __restrict__ idx_list,
                                const int* __restrict__ struct_id, float* out) {
  __shared__ float bins[NSTRUCT_];
  if (threadIdx.x < NSTRUCT_) bins[threadIdx.x] = 0.f;
  __syncthreads();
  int rr = blockIdx.x * 256 + threadIdx.x;
  if (rr < N_ATOMS) {
    int s = (rr >= offs[1]) + (rr >= offs[2]);
    float e = e_perm[rr] + b3[s] + comp_w[s];
    atomicAdd(&bins[struct_id[idx_list[rr]]], e);
  }
  __syncthreads();
  if (threadIdx.x < NSTRUCT_) atomicAdd(&out[threadIdx.x], bins[threadIdx.x]);
}

// ---------------- launch ----------------

extern "C" void kernel_launch(void* const* d_in, const int* in_sizes, int n_in,
                              void* d_out, int out_size, void* d_ws, size_t ws_size,
                              hipStream_t stream) {
  const float* features = (const float*)d_in[0];
  const float* ln_gamma = (const float*)d_in[1];
  const float* ln_beta = (const float*)d_in[2];
  const float* W1 = (const float*)d_in[3];
  const float* b1 = (const float*)d_in[4];
  const float* W2 = (const float*)d_in[5];
  const float* b2 = (const float*)d_in[6];
  const float* w3 = (const float*)d_in[7];
  const float* b3 = (const float*)d_in[8];
  const float* comp_w = (const float*)d_in[9];
  const int* species = (const int*)d_in[10];
  const int* struct_id = (const int*)d_in[11];
  float* out = (float*)d_out;

  char* ws = (char*)d_ws;
  size_t off = 0;
  auto alloc = [&](size_t bytes) {
    char* p = ws + off;
    off += (bytes + 255) & ~(size_t)255;
    return p;
  };
  bf16* W1T = (bf16*)alloc((size_t)S_NUM * H_DIM * F_DIM * 2);
  bf16* W2T = (bf16*)alloc((size_t)S_NUM * H_DIM * H_DIM * 2);
  bf16* xln = (bf16*)alloc((size_t)N_ATOMS * F_DIM * 2);
  bf16* h1 = (bf16*)alloc((size_t)N_ATOMS * H_DIM * 2);
  float* e_perm = (float*)alloc((size_t)N_ATOMS * 4);
  int* idx_list = (int*)alloc((size_t)N_ATOMS * 4);
  int* pos_of = (int*)alloc((size_t)N_ATOMS * 4);
  int* ints = (int*)alloc(64);
  int* cnt = ints;
  int* pos = ints + 3;
  int* offs = ints + 6;

  int nb = (N_ATOMS + 255) / 256;
  init_kernel<<<nb, 256, 0, stream>>>(e_perm, out, ints);
  count_kernel<<<nb, 256, 0, stream>>>(species, cnt);
  offs_kernel<<<1, 1, 0, stream>>>(cnt, offs);
  scatter_kernel<<<nb, 256, 0, stream>>>(species, pos, offs, idx_list, pos_of);
  transpose_kernel<<<dim3(H_DIM / 64, F_DIM / 64, S_NUM), 256, 0, stream>>>(W1, W1T, F_DIM, H_DIM);
  transpose_kernel<<<dim3(H_DIM / 64, H_DIM / 64, S_NUM), 256, 0, stream>>>(W2, W2T, H_DIM, H_DIM);
  ln_kernel<<<N_ATOMS, 256, 0, stream>>>(features, ln_gamma, ln_beta, species, pos_of, xln);

  int nby = (N_ATOMS + 127) / 128;  // 157
  gemm_kernel<0><<<4 * nby * S_NUM, 256, 0, stream>>>(xln, F_DIM, W1T, F_DIM, b1, nullptr, h1,
                                                      nullptr, offs, nby);
  gemm_kernel<1><<<4 * nby * S_NUM, 256, 0, stream>>>(h1, H_DIM, W2T, H_DIM, b2, w3, nullptr,
                                                      e_perm, offs, nby);
  finalize_kernel<<<nb, 256, 0, stream>>>(e_perm, offs, b3, comp_w, idx_list, struct_id, out);
}

// Round 4
// 157.030 us; speedup vs baseline: 3.5956x; 1.4157x over previous
//
#include <hip/hip_runtime.h>
#include <cstdint>
#include <cstddef>

#define N_ATOMS 20000
#define F_DIM 1920
#define H_DIM 512
#define S_NUM 3
#define NSTRUCT_ 16
#define MAXTILES 159  // ceil(20000/128) + (S_NUM-1)

typedef __bf16 bf16;
typedef __bf16 bf16x4 __attribute__((ext_vector_type(4)));
typedef __bf16 bf16x8 __attribute__((ext_vector_type(8)));
typedef float f32x4 __attribute__((ext_vector_type(4)));

__device__ __forceinline__ void gload_lds16(const void* g, void* l) {
  __builtin_amdgcn_global_load_lds(
      (const __attribute__((address_space(1))) unsigned int*)g,
      (__attribute__((address_space(3))) unsigned int*)l, 16, 0, 0);
}

// ---------------- routing / setup kernels ----------------

__global__ void init_kernel(float* e_perm, float* out, int* ints) {
  int i = blockIdx.x * 256 + threadIdx.x;
  if (i < N_ATOMS) e_perm[i] = 0.f;
  if (i < NSTRUCT_) out[i] = 0.f;
  if (i < 6) ints[i] = 0;  // cnt[0..2], pos[0..2]
}

// Wave-aggregated species histogram: 3 atomics per wave instead of 1 per thread.
__global__ void count_kernel(const int* __restrict__ species, int* cnt) {
  int i = blockIdx.x * 256 + threadIdx.x;
  int lane = threadIdx.x & 63;
  int sp = (i < N_ATOMS) ? species[i] : -1;
#pragma unroll
  for (int s = 0; s < S_NUM; ++s) {
    unsigned long long mask = __ballot(sp == s);
    if (mask && lane == (__ffsll((long long)mask) - 1))
      atomicAdd(&cnt[s], __popcll(mask));
  }
}

// offs[s]: row offsets; toffs[s]: 128-row tile offsets (flattened tile index).
__global__ void offs_kernel(const int* cnt, int* offs, int* toffs) {
  offs[0] = 0;
  offs[1] = cnt[0];
  offs[2] = cnt[0] + cnt[1];
  offs[3] = N_ATOMS;
  int t0 = (cnt[0] + 127) >> 7;
  int t1 = (cnt[1] + 127) >> 7;
  int t2 = (cnt[2] + 127) >> 7;
  toffs[0] = 0;
  toffs[1] = t0;
  toffs[2] = t0 + t1;
  toffs[3] = t0 + t1 + t2;
}

// Wave-aggregated scatter: one atomicAdd per wave per species; lane rank via
// ballot-prefix popcount. Any within-species order is valid (pos_of maps back).
__global__ void scatter_kernel(const int* __restrict__ species, int* pos,
                               const int* __restrict__ offs, int* idx_list, int* pos_of) {
  int i = blockIdx.x * 256 + threadIdx.x;
  int lane = threadIdx.x & 63;
  int sp = (i < N_ATOMS) ? species[i] : -1;
#pragma unroll
  for (int s = 0; s < S_NUM; ++s) {
    unsigned long long mask = __ballot(sp == s);
    if (!mask) continue;
    int leader = __ffsll((long long)mask) - 1;
    int base = 0;
    if (lane == leader) base = atomicAdd(&pos[s], __popcll(mask));
    base = __shfl(base, leader);
    if (sp == s) {
      int rank = __popcll(mask & ((1ULL << lane) - 1ULL));
      int p = offs[s] + base + rank;
      idx_list[p] = i;
      pos_of[i] = p;
    }
  }
}

// Transpose + bf16 convert: in f32 [S][R][C] -> out bf16 [S][C][R]
__global__ void transpose_kernel(const float* __restrict__ in, bf16* __restrict__ outp,
                                 int R, int C) {
  __shared__ float tile[64][65];
  int sp = blockIdx.z;
  const float* ins = in + (size_t)sp * R * C;
  bf16* outs = outp + (size_t)sp * R * C;
  int r0 = blockIdx.y * 64, c0 = blockIdx.x * 64;
  int tc = threadIdx.x & 63, tr4 = threadIdx.x >> 6;
#pragma unroll
  for (int it = 0; it < 16; ++it) {
    int r = it * 4 + tr4;
    tile[r][tc] = ins[(size_t)(r0 + r) * C + c0 + tc];
  }
  __syncthreads();
#pragma unroll
  for (int it = 0; it < 16; ++it) {
    int oc = it * 4 + tr4;
    outs[(size_t)(c0 + oc) * R + r0 + tc] = (bf16)tile[tc][oc];
  }
}

// ---------------- LayerNorm (writes bf16 rows in permuted order) ----------------

__global__ __launch_bounds__(256) void ln_kernel(
    const float* __restrict__ feat, const float* __restrict__ gamma,
    const float* __restrict__ beta, const int* __restrict__ species,
    const int* __restrict__ pos_of, bf16* __restrict__ xln) {
  int atom = blockIdx.x, tid = threadIdx.x;
  const float4* frow = (const float4*)(feat + (size_t)atom * F_DIM);
  float4 v0 = frow[tid];
  bool has2 = tid < 224;
  float4 v1 = has2 ? frow[256 + tid] : make_float4(0.f, 0.f, 0.f, 0.f);
  float s = v0.x + v0.y + v0.z + v0.w;
  float s2 = v0.x * v0.x + v0.y * v0.y + v0.z * v0.z + v0.w * v0.w;
  if (has2) {
    s += v1.x + v1.y + v1.z + v1.w;
    s2 += v1.x * v1.x + v1.y * v1.y + v1.z * v1.z + v1.w * v1.w;
  }
#pragma unroll
  for (int m = 1; m < 64; m <<= 1) {
    s += __shfl_xor(s, m);
    s2 += __shfl_xor(s2, m);
  }
  __shared__ float red[4][2];
  if ((tid & 63) == 0) { red[tid >> 6][0] = s; red[tid >> 6][1] = s2; }
  __syncthreads();
  s = red[0][0] + red[1][0] + red[2][0] + red[3][0];
  s2 = red[0][1] + red[1][1] + red[2][1] + red[3][1];
  float mu = s * (1.f / F_DIM);
  float var = s2 * (1.f / F_DIM) - mu * mu;
  float rsig = rsqrtf(var + 1e-5f);
  int sp = species[atom];
  size_t p = (size_t)pos_of[atom];
  const float4* g4 = (const float4*)(gamma + (size_t)sp * F_DIM);
  const float4* b4 = (const float4*)(beta + (size_t)sp * F_DIM);
  bf16* orow = xln + p * F_DIM;
  {
    float4 g = g4[tid], b = b4[tid];
    bf16x4 o;
    o[0] = (bf16)((v0.x - mu) * rsig * g.x + b.x);
    o[1] = (bf16)((v0.y - mu) * rsig * g.y + b.y);
    o[2] = (bf16)((v0.z - mu) * rsig * g.z + b.z);
    o[3] = (bf16)((v0.w - mu) * rsig * g.w + b.w);
    *(bf16x4*)(orow + 4 * tid) = o;
  }
  if (has2) {
    float4 g = g4[256 + tid], b = b4[256 + tid];
    bf16x4 o;
    o[0] = (bf16)((v1.x - mu) * rsig * g.x + b.x);
    o[1] = (bf16)((v1.y - mu) * rsig * g.y + b.y);
    o[2] = (bf16)((v1.z - mu) * rsig * g.z + b.z);
    o[3] = (bf16)((v1.w - mu) * rsig * g.w + b.w);
    *(bf16x4*)(orow + 4 * (256 + tid)) = o;
  }
}

// ---------------- bf16 MFMA GEMM, 128x128 tile, BK=64, single-buffer 32KB ----------
// Flattened tile index: block decodes t -> (sp, by) via toffs so ~all blocks are
// live and the XCD swizzle spreads work evenly (R3 fix: 2/3-dead grid clustered
// live blocks on 3 of 8 XCDs -> occupancy 11.5%).
// A: [rows][lda_e] bf16 (permuted, species-contiguous). BT: [S][512][K] bf16.
// EPI 0: Hout[r][c] = silu(acc + bias[c])   (h1)
// EPI 1: e_perm[r] += sum_c silu(acc + bias[c]) * w3[c]

template <int EPI>
__global__ __launch_bounds__(256, 4) void gemm_kernel(
    const bf16* __restrict__ A, int lda_e, const bf16* __restrict__ BT, int K,
    const float* __restrict__ bias, const float* __restrict__ w3,
    bf16* __restrict__ Hout, float* __restrict__ e_perm,
    const int* __restrict__ offs, const int* __restrict__ toffs) {
  __shared__ char smem[2][16384];  // [A/B][128 rows x 64 k x bf16], single buffer

  int total = gridDim.x;
  int lid = blockIdx.x;
  // bijective XCD-chunk swizzle (m204)
  int q = total >> 3, r = total & 7;
  int xcd = lid & 7, sl = lid >> 3;
  int w = (xcd < r ? xcd * (q + 1) : r * (q + 1) + (xcd - r) * q) + sl;
  int bx = w & 3;
  int t = w >> 2;
  if (t >= toffs[3]) return;
  int sp = (t >= toffs[1]) + (t >= toffs[2]);
  int by = t - toffs[sp];

  int rstart = offs[sp], rend = offs[sp + 1];
  int r0 = rstart + by * 128;

  int tid = threadIdx.x;
  int lane = tid & 63, wid = tid >> 6;
  int wm = wid >> 1, wn = wid & 1;
  int n0 = bx * 128;

  const char* Ag = (const char*)A;
  size_t ldab = (size_t)lda_e * 2;
  const char* Bg = (const char*)(BT + (size_t)sp * H_DIM * K);
  size_t ldbb = (size_t)K * 2;

  int l8 = lane >> 3;
  int sw_st = (((lane & 7) ^ l8) << 4);  // inverse-swizzled source byte (involution)

  auto stage = [&](int kt) {
    int k0b = kt * 128;  // kt*64 elems * 2B
#pragma unroll
    for (int t_ = 0; t_ < 4; ++t_) {
      int chunk = t_ * 4 + wid;      // 0..15, wave-uniform
      int row = chunk * 8 + l8;      // 0..127 (per-lane)
      int ar = r0 + row;
      if (ar > rend - 1) ar = rend - 1;
      gload_lds16(Ag + (size_t)ar * ldab + k0b + sw_st, &smem[0][chunk * 1024]);
      gload_lds16(Bg + (size_t)(n0 + row) * ldbb + k0b + sw_st, &smem[1][chunk * 1024]);
    }
  };

  f32x4 acc[4][4];
#pragma unroll
  for (int a_ = 0; a_ < 4; ++a_)
#pragma unroll
    for (int b_ = 0; b_ < 4; ++b_) {
      f32x4 z = {0.f, 0.f, 0.f, 0.f};
      acc[a_][b_] = z;
    }

  int lr = lane & 15, lg = lane >> 4;
  int swr = (lr & 7) << 4;

  auto compute = [&]() {
    const char* Ab = smem[0];
    const char* Bb = smem[1];
#pragma unroll
    for (int kh = 0; kh < 2; ++kh) {
      int off = (kh * 64 + lg * 16) ^ swr;
      bf16x8 av[4], bv[4];
#pragma unroll
      for (int fm = 0; fm < 4; ++fm) {
        int row = wm * 64 + fm * 16 + lr;
        av[fm] = *(const bf16x8*)(Ab + row * 128 + off);
      }
#pragma unroll
      for (int fn = 0; fn < 4; ++fn) {
        int row = wn * 64 + fn * 16 + lr;
        bv[fn] = *(const bf16x8*)(Bb + row * 128 + off);
      }
#pragma unroll
      for (int fm = 0; fm < 4; ++fm)
#pragma unroll
        for (int fn = 0; fn < 4; ++fn)
          acc[fm][fn] =
              __builtin_amdgcn_mfma_f32_16x16x32_bf16(av[fm], bv[fn], acc[fm][fn], 0, 0, 0);
    }
  };

  int NT = K / 64;
#pragma unroll 1
  for (int kt = 0; kt < NT; ++kt) {
    stage(kt);
    __syncthreads();
    compute();
    __syncthreads();
  }

  const float* bs = bias + sp * H_DIM;
  if (EPI == 0) {
#pragma unroll
    for (int fm = 0; fm < 4; ++fm)
#pragma unroll
      for (int i = 0; i < 4; ++i) {
        int rr = r0 + wm * 64 + fm * 16 + lg * 4 + i;
        if (rr < rend) {
#pragma unroll
          for (int fn = 0; fn < 4; ++fn) {
            int c = n0 + wn * 64 + fn * 16 + lr;
            float x = acc[fm][fn][i] + bs[c];
            float h = x / (1.f + __expf(-x));
            Hout[(size_t)rr * H_DIM + c] = (bf16)h;
          }
        }
      }
  } else {
    const float* ws3 = w3 + sp * H_DIM;
#pragma unroll
    for (int fm = 0; fm < 4; ++fm)
#pragma unroll
      for (int i = 0; i < 4; ++i) {
        int rr = r0 + wm * 64 + fm * 16 + lg * 4 + i;
        float part = 0.f;
#pragma unroll
        for (int fn = 0; fn < 4; ++fn) {
          int c = n0 + wn * 64 + fn * 16 + lr;
          float x = acc[fm][fn][i] + bs[c];
          part += (x / (1.f + __expf(-x))) * ws3[c];
        }
        part += __shfl_xor(part, 1);
        part += __shfl_xor(part, 2);
        part += __shfl_xor(part, 4);
        part += __shfl_xor(part, 8);
        if (lr == 0 && rr < rend) atomicAdd(&e_perm[rr], part);
      }
  }
}

// ---------------- finalize: + b3 + comp_w, segment-sum (block-local bins) ----------------

__global__ void finalize_kernel(const float* __restrict__ e_perm, const int* __restrict__ offs,
                                const float* __restrict__ b3, const float* __restrict__ comp_w,
                                const int* __restrict__ idx_list,
                                const int* __restrict__ struct_id, float* out) {
  __shared__ float bins[NSTRUCT_];
  if (threadIdx.x < NSTRUCT_) bins[threadIdx.x] = 0.f;
  __syncthreads();
  int rr = blockIdx.x * 256 + threadIdx.x;
  if (rr < N_ATOMS) {
    int s = (rr >= offs[1]) + (rr >= offs[2]);
    float e = e_perm[rr] + b3[s] + comp_w[s];
    atomicAdd(&bins[struct_id[idx_list[rr]]], e);
  }
  __syncthreads();
  if (threadIdx.x < NSTRUCT_) atomicAdd(&out[threadIdx.x], bins[threadIdx.x]);
}

// ---------------- launch ----------------

extern "C" void kernel_launch(void* const* d_in, const int* in_sizes, int n_in,
                              void* d_out, int out_size, void* d_ws, size_t ws_size,
                              hipStream_t stream) {
  const float* features = (const float*)d_in[0];
  const float* ln_gamma = (const float*)d_in[1];
  const float* ln_beta = (const float*)d_in[2];
  const float* W1 = (const float*)d_in[3];
  const float* b1 = (const float*)d_in[4];
  const float* W2 = (const float*)d_in[5];
  const float* b2 = (const float*)d_in[6];
  const float* w3 = (const float*)d_in[7];
  const float* b3 = (const float*)d_in[8];
  const float* comp_w = (const float*)d_in[9];
  const int* species = (const int*)d_in[10];
  const int* struct_id = (const int*)d_in[11];
  float* out = (float*)d_out;

  char* ws = (char*)d_ws;
  size_t off = 0;
  auto alloc = [&](size_t bytes) {
    char* p = ws + off;
    off += (bytes + 255) & ~(size_t)255;
    return p;
  };
  bf16* W1T = (bf16*)alloc((size_t)S_NUM * H_DIM * F_DIM * 2);
  bf16* W2T = (bf16*)alloc((size_t)S_NUM * H_DIM * H_DIM * 2);
  bf16* xln = (bf16*)alloc((size_t)N_ATOMS * F_DIM * 2);
  bf16* h1 = (bf16*)alloc((size_t)N_ATOMS * H_DIM * 2);
  float* e_perm = (float*)alloc((size_t)N_ATOMS * 4);
  int* idx_list = (int*)alloc((size_t)N_ATOMS * 4);
  int* pos_of = (int*)alloc((size_t)N_ATOMS * 4);
  int* ints = (int*)alloc(64);
  int* cnt = ints;
  int* pos = ints + 3;
  int* offs = ints + 6;
  int* toffs = ints + 10;

  int nb = (N_ATOMS + 255) / 256;
  init_kernel<<<nb, 256, 0, stream>>>(e_perm, out, ints);
  count_kernel<<<nb, 256, 0, stream>>>(species, cnt);
  offs_kernel<<<1, 1, 0, stream>>>(cnt, offs, toffs);
  scatter_kernel<<<nb, 256, 0, stream>>>(species, pos, offs, idx_list, pos_of);
  transpose_kernel<<<dim3(H_DIM / 64, F_DIM / 64, S_NUM), 256, 0, stream>>>(W1, W1T, F_DIM, H_DIM);
  transpose_kernel<<<dim3(H_DIM / 64, H_DIM / 64, S_NUM), 256, 0, stream>>>(W2, W2T, H_DIM, H_DIM);
  ln_kernel<<<N_ATOMS, 256, 0, stream>>>(features, ln_gamma, ln_beta, species, pos_of, xln);

  gemm_kernel<0><<<4 * MAXTILES, 256, 0, stream>>>(xln, F_DIM, W1T, F_DIM, b1, nullptr, h1,
                                                   nullptr, offs, toffs);
  gemm_kernel<1><<<4 * MAXTILES, 256, 0, stream>>>(h1, H_DIM, W2T, H_DIM, b2, w3, nullptr,
                                                   e_perm, offs, toffs);
  finalize_kernel<<<nb, 256, 0, stream>>>(e_perm, offs, b3, comp_w, idx_list, struct_id, out);
}

// Round 5
// 155.836 us; speedup vs baseline: 3.6232x; 1.0077x over previous
//
#include <hip/hip_runtime.h>
#include <cstdint>
#include <cstddef>

#define N_ATOMS 20000
#define F_DIM 1920
#define H_DIM 512
#define S_NUM 3
#define NSTRUCT_ 16
#define MAXTILES 159  // ceil(20000/128) + (S_NUM-1)

typedef __bf16 bf16;
typedef __bf16 bf16x4 __attribute__((ext_vector_type(4)));
typedef __bf16 bf16x8 __attribute__((ext_vector_type(8)));
typedef float f32x4 __attribute__((ext_vector_type(4)));

__device__ __forceinline__ void gload_lds16(const void* g, void* l) {
  __builtin_amdgcn_global_load_lds(
      (const __attribute__((address_space(1))) unsigned int*)g,
      (__attribute__((address_space(3))) unsigned int*)l, 16, 0, 0);
}

// ---------------- routing / setup kernels ----------------

__global__ void init_kernel(float* out, int* ints) {
  int i = threadIdx.x;
  if (i < NSTRUCT_) out[i] = 0.f;
  if (i < 6) ints[i] = 0;  // cnt[0..2], pos[0..2]
}

// Wave-aggregated species histogram: 3 atomics per wave instead of 1 per thread.
__global__ void count_kernel(const int* __restrict__ species, int* cnt) {
  int i = blockIdx.x * 256 + threadIdx.x;
  int lane = threadIdx.x & 63;
  int sp = (i < N_ATOMS) ? species[i] : -1;
#pragma unroll
  for (int s = 0; s < S_NUM; ++s) {
    unsigned long long mask = __ballot(sp == s);
    if (mask && lane == (__ffsll((long long)mask) - 1))
      atomicAdd(&cnt[s], __popcll(mask));
  }
}

// offs[s]: row offsets; toffs[s]: 128-row tile offsets (flattened tile index).
__global__ void offs_kernel(const int* cnt, int* offs, int* toffs) {
  offs[0] = 0;
  offs[1] = cnt[0];
  offs[2] = cnt[0] + cnt[1];
  offs[3] = N_ATOMS;
  int t0 = (cnt[0] + 127) >> 7;
  int t1 = (cnt[1] + 127) >> 7;
  int t2 = (cnt[2] + 127) >> 7;
  toffs[0] = 0;
  toffs[1] = t0;
  toffs[2] = t0 + t1;
  toffs[3] = t0 + t1 + t2;
}

// Wave-aggregated scatter: one atomicAdd per wave per species; lane rank via
// ballot-prefix popcount. Any within-species order is valid (pos_of maps back).
__global__ void scatter_kernel(const int* __restrict__ species, int* pos,
                               const int* __restrict__ offs, int* idx_list, int* pos_of) {
  int i = blockIdx.x * 256 + threadIdx.x;
  int lane = threadIdx.x & 63;
  int sp = (i < N_ATOMS) ? species[i] : -1;
#pragma unroll
  for (int s = 0; s < S_NUM; ++s) {
    unsigned long long mask = __ballot(sp == s);
    if (!mask) continue;
    int leader = __ffsll((long long)mask) - 1;
    int base = 0;
    if (lane == leader) base = atomicAdd(&pos[s], __popcll(mask));
    base = __shfl(base, leader);
    if (sp == s) {
      int rank = __popcll(mask & ((1ULL << lane) - 1ULL));
      int p = offs[s] + base + rank;
      idx_list[p] = i;
      pos_of[i] = p;
    }
  }
}

// Merged transpose + bf16 convert for W1 and W2 in one launch.
// W1: f32 [S][1920][512] -> bf16 [S][512][1920]   (720 tiles of 64x64)
// W2: f32 [S][512][512]  -> bf16 [S][512][512]    (192 tiles)
__global__ void transpose_kernel(const float* __restrict__ W1, bf16* __restrict__ W1T,
                                 const float* __restrict__ W2, bf16* __restrict__ W2T) {
  __shared__ float tile[64][65];
  int id = blockIdx.x;
  const float* ins;
  bf16* outs;
  int R, C, r0, c0;
  if (id < 720) {
    int sp = id / 240, rem = id % 240;
    R = F_DIM; C = H_DIM;
    c0 = (rem & 7) * 64;
    r0 = (rem >> 3) * 64;
    ins = W1 + (size_t)sp * R * C;
    outs = W1T + (size_t)sp * R * C;
  } else {
    int id2 = id - 720;
    int sp = id2 / 64, rem = id2 % 64;
    R = H_DIM; C = H_DIM;
    c0 = (rem & 7) * 64;
    r0 = (rem >> 3) * 64;
    ins = W2 + (size_t)sp * R * C;
    outs = W2T + (size_t)sp * R * C;
  }
  int tc = threadIdx.x & 63, tr4 = threadIdx.x >> 6;
#pragma unroll
  for (int it = 0; it < 16; ++it) {
    int r = it * 4 + tr4;
    tile[r][tc] = ins[(size_t)(r0 + r) * C + c0 + tc];
  }
  __syncthreads();
#pragma unroll
  for (int it = 0; it < 16; ++it) {
    int oc = it * 4 + tr4;
    outs[(size_t)(c0 + oc) * R + r0 + tc] = (bf16)tile[tc][oc];
  }
}

// ---------------- LayerNorm (writes bf16 rows in permuted order) ----------------

__global__ __launch_bounds__(256) void ln_kernel(
    const float* __restrict__ feat, const float* __restrict__ gamma,
    const float* __restrict__ beta, const int* __restrict__ species,
    const int* __restrict__ pos_of, bf16* __restrict__ xln) {
  int atom = blockIdx.x, tid = threadIdx.x;
  const float4* frow = (const float4*)(feat + (size_t)atom * F_DIM);
  float4 v0 = frow[tid];
  bool has2 = tid < 224;
  float4 v1 = has2 ? frow[256 + tid] : make_float4(0.f, 0.f, 0.f, 0.f);
  float s = v0.x + v0.y + v0.z + v0.w;
  float s2 = v0.x * v0.x + v0.y * v0.y + v0.z * v0.z + v0.w * v0.w;
  if (has2) {
    s += v1.x + v1.y + v1.z + v1.w;
    s2 += v1.x * v1.x + v1.y * v1.y + v1.z * v1.z + v1.w * v1.w;
  }
#pragma unroll
  for (int m = 1; m < 64; m <<= 1) {
    s += __shfl_xor(s, m);
    s2 += __shfl_xor(s2, m);
  }
  __shared__ float red[4][2];
  if ((tid & 63) == 0) { red[tid >> 6][0] = s; red[tid >> 6][1] = s2; }
  __syncthreads();
  s = red[0][0] + red[1][0] + red[2][0] + red[3][0];
  s2 = red[0][1] + red[1][1] + red[2][1] + red[3][1];
  float mu = s * (1.f / F_DIM);
  float var = s2 * (1.f / F_DIM) - mu * mu;
  float rsig = rsqrtf(var + 1e-5f);
  int sp = species[atom];
  size_t p = (size_t)pos_of[atom];
  const float4* g4 = (const float4*)(gamma + (size_t)sp * F_DIM);
  const float4* b4 = (const float4*)(beta + (size_t)sp * F_DIM);
  bf16* orow = xln + p * F_DIM;
  {
    float4 g = g4[tid], b = b4[tid];
    bf16x4 o;
    o[0] = (bf16)((v0.x - mu) * rsig * g.x + b.x);
    o[1] = (bf16)((v0.y - mu) * rsig * g.y + b.y);
    o[2] = (bf16)((v0.z - mu) * rsig * g.z + b.z);
    o[3] = (bf16)((v0.w - mu) * rsig * g.w + b.w);
    *(bf16x4*)(orow + 4 * tid) = o;
  }
  if (has2) {
    float4 g = g4[256 + tid], b = b4[256 + tid];
    bf16x4 o;
    o[0] = (bf16)((v1.x - mu) * rsig * g.x + b.x);
    o[1] = (bf16)((v1.y - mu) * rsig * g.y + b.y);
    o[2] = (bf16)((v1.z - mu) * rsig * g.z + b.z);
    o[3] = (bf16)((v1.w - mu) * rsig * g.w + b.w);
    *(bf16x4*)(orow + 4 * (256 + tid)) = o;
  }
}

// ---------------- bf16 MFMA GEMM, 128x128 tile, BK=64, single-buffer 32KB ----------
// Flattened tile index: block decodes t -> (sp, by) via toffs so ~all blocks are
// live and the XCD swizzle spreads work evenly.
// A: [rows][lda_e] bf16 (permuted, species-contiguous). BT: [S][512][K] bf16.
// EPI 0: Hout[r][c] = silu(acc + bias[c])   (h1)
// EPI 1: e_part[(bx*2+wn)][r] = sum_c silu(acc + bias[c]) * w3[c]  (plain store)

template <int EPI>
__global__ __launch_bounds__(256, 4) void gemm_kernel(
    const bf16* __restrict__ A, int lda_e, const bf16* __restrict__ BT, int K,
    const float* __restrict__ bias, const float* __restrict__ w3,
    bf16* __restrict__ Hout, float* __restrict__ e_part,
    const int* __restrict__ offs, const int* __restrict__ toffs) {
  __shared__ char smem[2][16384];  // [A/B][128 rows x 64 k x bf16], single buffer

  int total = gridDim.x;
  int lid = blockIdx.x;
  // bijective XCD-chunk swizzle (m204)
  int q = total >> 3, r = total & 7;
  int xcd = lid & 7, sl = lid >> 3;
  int w = (xcd < r ? xcd * (q + 1) : r * (q + 1) + (xcd - r) * q) + sl;
  int bx = w & 3;
  int t = w >> 2;
  if (t >= toffs[3]) return;
  int sp = (t >= toffs[1]) + (t >= toffs[2]);
  int by = t - toffs[sp];

  int rstart = offs[sp], rend = offs[sp + 1];
  int r0 = rstart + by * 128;

  int tid = threadIdx.x;
  int lane = tid & 63, wid = tid >> 6;
  int wm = wid >> 1, wn = wid & 1;
  int n0 = bx * 128;

  const char* Ag = (const char*)A;
  size_t ldab = (size_t)lda_e * 2;
  const char* Bg = (const char*)(BT + (size_t)sp * H_DIM * K);
  size_t ldbb = (size_t)K * 2;

  int l8 = lane >> 3;
  int sw_st = (((lane & 7) ^ l8) << 4);  // inverse-swizzled source byte (involution)

  auto stage = [&](int kt) {
    int k0b = kt * 128;  // kt*64 elems * 2B
#pragma unroll
    for (int t_ = 0; t_ < 4; ++t_) {
      int chunk = t_ * 4 + wid;      // 0..15, wave-uniform
      int row = chunk * 8 + l8;      // 0..127 (per-lane)
      int ar = r0 + row;
      if (ar > rend - 1) ar = rend - 1;
      gload_lds16(Ag + (size_t)ar * ldab + k0b + sw_st, &smem[0][chunk * 1024]);
      gload_lds16(Bg + (size_t)(n0 + row) * ldbb + k0b + sw_st, &smem[1][chunk * 1024]);
    }
  };

  f32x4 acc[4][4];
#pragma unroll
  for (int a_ = 0; a_ < 4; ++a_)
#pragma unroll
    for (int b_ = 0; b_ < 4; ++b_) {
      f32x4 z = {0.f, 0.f, 0.f, 0.f};
      acc[a_][b_] = z;
    }

  int lr = lane & 15, lg = lane >> 4;
  int swr = (lr & 7) << 4;

  auto compute = [&]() {
    const char* Ab = smem[0];
    const char* Bb = smem[1];
#pragma unroll
    for (int kh = 0; kh < 2; ++kh) {
      int off = (kh * 64 + lg * 16) ^ swr;
      bf16x8 av[4], bv[4];
#pragma unroll
      for (int fm = 0; fm < 4; ++fm) {
        int row = wm * 64 + fm * 16 + lr;
        av[fm] = *(const bf16x8*)(Ab + row * 128 + off);
      }
#pragma unroll
      for (int fn = 0; fn < 4; ++fn) {
        int row = wn * 64 + fn * 16 + lr;
        bv[fn] = *(const bf16x8*)(Bb + row * 128 + off);
      }
#pragma unroll
      for (int fm = 0; fm < 4; ++fm)
#pragma unroll
        for (int fn = 0; fn < 4; ++fn)
          acc[fm][fn] =
              __builtin_amdgcn_mfma_f32_16x16x32_bf16(av[fm], bv[fn], acc[fm][fn], 0, 0, 0);
    }
  };

  int NT = K / 64;
#pragma unroll 1
  for (int kt = 0; kt < NT; ++kt) {
    stage(kt);
    __syncthreads();
    compute();
    __syncthreads();
  }

  const float* bs = bias + sp * H_DIM;
  if (EPI == 0) {
#pragma unroll
    for (int fm = 0; fm < 4; ++fm)
#pragma unroll
      for (int i = 0; i < 4; ++i) {
        int rr = r0 + wm * 64 + fm * 16 + lg * 4 + i;
        if (rr < rend) {
#pragma unroll
          for (int fn = 0; fn < 4; ++fn) {
            int c = n0 + wn * 64 + fn * 16 + lr;
            float x = acc[fm][fn][i] + bs[c];
            float h = x / (1.f + __expf(-x));
            Hout[(size_t)rr * H_DIM + c] = (bf16)h;
          }
        }
      }
  } else {
    const float* ws3 = w3 + sp * H_DIM;
    float* ep = e_part + (size_t)(bx * 2 + wn) * N_ATOMS;
#pragma unroll
    for (int fm = 0; fm < 4; ++fm)
#pragma unroll
      for (int i = 0; i < 4; ++i) {
        int rr = r0 + wm * 64 + fm * 16 + lg * 4 + i;
        float part = 0.f;
#pragma unroll
        for (int fn = 0; fn < 4; ++fn) {
          int c = n0 + wn * 64 + fn * 16 + lr;
          float x = acc[fm][fn][i] + bs[c];
          part += (x / (1.f + __expf(-x))) * ws3[c];
        }
        part += __shfl_xor(part, 1);
        part += __shfl_xor(part, 2);
        part += __shfl_xor(part, 4);
        part += __shfl_xor(part, 8);
        if (lr == 0 && rr < rend) ep[rr] = part;  // non-atomic partial
      }
  }
}

// ---------------- finalize: sum 8 partials, + b3 + comp_w, segment-sum ----------------

__global__ void finalize_kernel(const float* __restrict__ e_part, const int* __restrict__ offs,
                                const float* __restrict__ b3, const float* __restrict__ comp_w,
                                const int* __restrict__ idx_list,
                                const int* __restrict__ struct_id, float* out) {
  __shared__ float bins[NSTRUCT_];
  if (threadIdx.x < NSTRUCT_) bins[threadIdx.x] = 0.f;
  __syncthreads();
  int rr = blockIdx.x * 256 + threadIdx.x;
  if (rr < N_ATOMS) {
    float e = 0.f;
#pragma unroll
    for (int p = 0; p < 8; ++p) e += e_part[(size_t)p * N_ATOMS + rr];
    int s = (rr >= offs[1]) + (rr >= offs[2]);
    e += b3[s] + comp_w[s];
    atomicAdd(&bins[struct_id[idx_list[rr]]], e);
  }
  __syncthreads();
  if (threadIdx.x < NSTRUCT_) atomicAdd(&out[threadIdx.x], bins[threadIdx.x]);
}

// ---------------- launch ----------------

extern "C" void kernel_launch(void* const* d_in, const int* in_sizes, int n_in,
                              void* d_out, int out_size, void* d_ws, size_t ws_size,
                              hipStream_t stream) {
  const float* features = (const float*)d_in[0];
  const float* ln_gamma = (const float*)d_in[1];
  const float* ln_beta = (const float*)d_in[2];
  const float* W1 = (const float*)d_in[3];
  const float* b1 = (const float*)d_in[4];
  const float* W2 = (const float*)d_in[5];
  const float* b2 = (const float*)d_in[6];
  const float* w3 = (const float*)d_in[7];
  const float* b3 = (const float*)d_in[8];
  const float* comp_w = (const float*)d_in[9];
  const int* species = (const int*)d_in[10];
  const int* struct_id = (const int*)d_in[11];
  float* out = (float*)d_out;

  char* ws = (char*)d_ws;
  size_t off = 0;
  auto alloc = [&](size_t bytes) {
    char* p = ws + off;
    off += (bytes + 255) & ~(size_t)255;
    return p;
  };
  bf16* W1T = (bf16*)alloc((size_t)S_NUM * H_DIM * F_DIM * 2);
  bf16* W2T = (bf16*)alloc((size_t)S_NUM * H_DIM * H_DIM * 2);
  bf16* xln = (bf16*)alloc((size_t)N_ATOMS * F_DIM * 2);
  bf16* h1 = (bf16*)alloc((size_t)N_ATOMS * H_DIM * 2);
  float* e_part = (float*)alloc((size_t)8 * N_ATOMS * 4);
  int* idx_list = (int*)alloc((size_t)N_ATOMS * 4);
  int* pos_of = (int*)alloc((size_t)N_ATOMS * 4);
  int* ints = (int*)alloc(64);
  int* cnt = ints;
  int* pos = ints + 3;
  int* offs = ints + 6;
  int* toffs = ints + 10;

  int nb = (N_ATOMS + 255) / 256;
  init_kernel<<<1, 64, 0, stream>>>(out, ints);
  count_kernel<<<nb, 256, 0, stream>>>(species, cnt);
  offs_kernel<<<1, 1, 0, stream>>>(cnt, offs, toffs);
  scatter_kernel<<<nb, 256, 0, stream>>>(species, pos, offs, idx_list, pos_of);
  transpose_kernel<<<912, 256, 0, stream>>>(W1, W1T, W2, W2T);
  ln_kernel<<<N_ATOMS, 256, 0, stream>>>(features, ln_gamma, ln_beta, species, pos_of, xln);

  gemm_kernel<0><<<4 * MAXTILES, 256, 0, stream>>>(xln, F_DIM, W1T, F_DIM, b1, nullptr, h1,
                                                   nullptr, offs, toffs);
  gemm_kernel<1><<<4 * MAXTILES, 256, 0, stream>>>(h1, H_DIM, W2T, H_DIM, b2, w3, nullptr,
                                                   e_part, offs, toffs);
  finalize_kernel<<<nb, 256, 0, stream>>>(e_part, offs, b3, comp_w, idx_list, struct_id, out);
}

// Round 6
// 152.627 us; speedup vs baseline: 3.6994x; 1.0210x over previous
//
#include <hip/hip_runtime.h>
#include <cstdint>
#include <cstddef>

#define N_ATOMS 20000
#define F_DIM 1920
#define H_DIM 512
#define S_NUM 3
#define NSTRUCT_ 16
#define MAXT64 315  // ceil(20000/64) + (S_NUM-1)

typedef __bf16 bf16;
typedef __bf16 bf16x4 __attribute__((ext_vector_type(4)));
typedef __bf16 bf16x8 __attribute__((ext_vector_type(8)));
typedef float f32x4 __attribute__((ext_vector_type(4)));

__device__ __forceinline__ void gload_lds16(const void* g, void* l) {
  __builtin_amdgcn_global_load_lds(
      (const __attribute__((address_space(1))) unsigned int*)g,
      (__attribute__((address_space(3))) unsigned int*)l, 16, 0, 0);
}

// ---------------- routing / setup ----------------

// Fused init + count + offs: one block, 1024 threads.
__global__ __launch_bounds__(1024) void count_offs_kernel(const int* __restrict__ species,
                                                          int* ints, float* out) {
  __shared__ int lcnt[3];
  int tid = threadIdx.x;
  if (tid < 3) lcnt[tid] = 0;
  if (tid < NSTRUCT_) out[tid] = 0.f;
  __syncthreads();
  int c0 = 0, c1 = 0, c2 = 0;
  for (int i = tid; i < N_ATOMS; i += 1024) {
    int s = species[i];
    c0 += (s == 0);
    c1 += (s == 1);
    c2 += (s == 2);
  }
#pragma unroll
  for (int m = 1; m < 64; m <<= 1) {
    c0 += __shfl_xor(c0, m);
    c1 += __shfl_xor(c1, m);
    c2 += __shfl_xor(c2, m);
  }
  if ((tid & 63) == 0) {
    atomicAdd(&lcnt[0], c0);
    atomicAdd(&lcnt[1], c1);
    atomicAdd(&lcnt[2], c2);
  }
  __syncthreads();
  if (tid == 0) {
    int n0 = lcnt[0], n1 = lcnt[1], n2 = lcnt[2];
    int* pos = ints;
    int* offs = ints + 6;
    int* toffs = ints + 10;
    pos[0] = pos[1] = pos[2] = 0;
    offs[0] = 0;
    offs[1] = n0;
    offs[2] = n0 + n1;
    offs[3] = N_ATOMS;
    int t0 = (n0 + 63) >> 6, t1 = (n1 + 63) >> 6, t2 = (n2 + 63) >> 6;
    toffs[0] = 0;
    toffs[1] = t0;
    toffs[2] = t0 + t1;
    toffs[3] = t0 + t1 + t2;
  }
}

// Wave-aggregated scatter: one atomicAdd per wave per species; lane rank via
// ballot-prefix popcount. Any within-species order is valid (pos_of maps back).
__global__ void scatter_kernel(const int* __restrict__ species, int* pos,
                               const int* __restrict__ offs, int* idx_list, int* pos_of) {
  int i = blockIdx.x * 256 + threadIdx.x;
  int lane = threadIdx.x & 63;
  int sp = (i < N_ATOMS) ? species[i] : -1;
#pragma unroll
  for (int s = 0; s < S_NUM; ++s) {
    unsigned long long mask = __ballot(sp == s);
    if (!mask) continue;
    int leader = __ffsll((long long)mask) - 1;
    int base = 0;
    if (lane == leader) base = atomicAdd(&pos[s], __popcll(mask));
    base = __shfl(base, leader);
    if (sp == s) {
      int rank = __popcll(mask & ((1ULL << lane) - 1ULL));
      int p = offs[s] + base + rank;
      idx_list[p] = i;
      pos_of[i] = p;
    }
  }
}

// Merged transpose + bf16 convert for W1 and W2 in one launch.
__global__ void transpose_kernel(const float* __restrict__ W1, bf16* __restrict__ W1T,
                                 const float* __restrict__ W2, bf16* __restrict__ W2T) {
  __shared__ float tile[64][65];
  int id = blockIdx.x;
  const float* ins;
  bf16* outs;
  int R, C, r0, c0;
  if (id < 720) {
    int sp = id / 240, rem = id % 240;
    R = F_DIM;
    C = H_DIM;
    c0 = (rem & 7) * 64;
    r0 = (rem >> 3) * 64;
    ins = W1 + (size_t)sp * R * C;
    outs = W1T + (size_t)sp * R * C;
  } else {
    int id2 = id - 720;
    int sp = id2 / 64, rem = id2 % 64;
    R = H_DIM;
    C = H_DIM;
    c0 = (rem & 7) * 64;
    r0 = (rem >> 3) * 64;
    ins = W2 + (size_t)sp * R * C;
    outs = W2T + (size_t)sp * R * C;
  }
  int tc = threadIdx.x & 63, tr4 = threadIdx.x >> 6;
#pragma unroll
  for (int it = 0; it < 16; ++it) {
    int r = it * 4 + tr4;
    tile[r][tc] = ins[(size_t)(r0 + r) * C + c0 + tc];
  }
  __syncthreads();
#pragma unroll
  for (int it = 0; it < 16; ++it) {
    int oc = it * 4 + tr4;
    outs[(size_t)(c0 + oc) * R + r0 + tc] = (bf16)tile[tc][oc];
  }
}

// ---------------- LayerNorm (writes bf16 rows in permuted order) ----------------

__global__ __launch_bounds__(256) void ln_kernel(
    const float* __restrict__ feat, const float* __restrict__ gamma,
    const float* __restrict__ beta, const int* __restrict__ species,
    const int* __restrict__ pos_of, bf16* __restrict__ xln) {
  int atom = blockIdx.x, tid = threadIdx.x;
  const float4* frow = (const float4*)(feat + (size_t)atom * F_DIM);
  float4 v0 = frow[tid];
  bool has2 = tid < 224;
  float4 v1 = has2 ? frow[256 + tid] : make_float4(0.f, 0.f, 0.f, 0.f);
  float s = v0.x + v0.y + v0.z + v0.w;
  float s2 = v0.x * v0.x + v0.y * v0.y + v0.z * v0.z + v0.w * v0.w;
  if (has2) {
    s += v1.x + v1.y + v1.z + v1.w;
    s2 += v1.x * v1.x + v1.y * v1.y + v1.z * v1.z + v1.w * v1.w;
  }
#pragma unroll
  for (int m = 1; m < 64; m <<= 1) {
    s += __shfl_xor(s, m);
    s2 += __shfl_xor(s2, m);
  }
  __shared__ float red[4][2];
  if ((tid & 63) == 0) { red[tid >> 6][0] = s; red[tid >> 6][1] = s2; }
  __syncthreads();
  s = red[0][0] + red[1][0] + red[2][0] + red[3][0];
  s2 = red[0][1] + red[1][1] + red[2][1] + red[3][1];
  float mu = s * (1.f / F_DIM);
  float var = s2 * (1.f / F_DIM) - mu * mu;
  float rsig = rsqrtf(var + 1e-5f);
  int sp = species[atom];
  size_t p = (size_t)pos_of[atom];
  const float4* g4 = (const float4*)(gamma + (size_t)sp * F_DIM);
  const float4* b4 = (const float4*)(beta + (size_t)sp * F_DIM);
  bf16* orow = xln + p * F_DIM;
  {
    float4 g = g4[tid], b = b4[tid];
    bf16x4 o;
    o[0] = (bf16)((v0.x - mu) * rsig * g.x + b.x);
    o[1] = (bf16)((v0.y - mu) * rsig * g.y + b.y);
    o[2] = (bf16)((v0.z - mu) * rsig * g.z + b.z);
    o[3] = (bf16)((v0.w - mu) * rsig * g.w + b.w);
    *(bf16x4*)(orow + 4 * tid) = o;
  }
  if (has2) {
    float4 g = g4[256 + tid], b = b4[256 + tid];
    bf16x4 o;
    o[0] = (bf16)((v1.x - mu) * rsig * g.x + b.x);
    o[1] = (bf16)((v1.y - mu) * rsig * g.y + b.y);
    o[2] = (bf16)((v1.z - mu) * rsig * g.z + b.z);
    o[3] = (bf16)((v1.w - mu) * rsig * g.w + b.w);
    *(bf16x4*)(orow + 4 * (256 + tid)) = o;
  }
}

// ---------------- bf16 MFMA GEMM, single-wave block, 64x128 tile, BK=64 ----------
// One 64-lane wave per block, fat wave-tile 64x128 (acc[4][8]): LDS reads per
// K-step drop to 24KB for 1.05 MFLOP (384 B/MFMA, was 512) -> MFMA-limited.
// Grid ~1260 blocks -> ~4.9/CU, tail imbalance ~2%.
// A: [rows][lda_e] bf16 (permuted). BT: [S][512][K] bf16.
// EPI 0: Hout[r][c] = silu(acc + bias[c])
// EPI 1: e_part[bx][r] = sum_c silu(acc + bias[c]) * w3[c]  (plain store)

template <int EPI>
__global__ __launch_bounds__(64, 2) void gemm_kernel(
    const bf16* __restrict__ A, int lda_e, const bf16* __restrict__ BT, int K,
    const float* __restrict__ bias, const float* __restrict__ w3,
    bf16* __restrict__ Hout, float* __restrict__ e_part,
    const int* __restrict__ offs, const int* __restrict__ toffs) {
  __shared__ char smem[24576];  // A: 64x64 bf16 @0 (8KB), B: 128x64 @8192 (16KB)

  int total = gridDim.x;
  int lid = blockIdx.x;
  // bijective XCD-chunk swizzle (m204)
  int q = total >> 3, r = total & 7;
  int xcd = lid & 7, sl = lid >> 3;
  int w = (xcd < r ? xcd * (q + 1) : r * (q + 1) + (xcd - r) * q) + sl;
  int bx = w & 3;
  int t = w >> 2;
  if (t >= toffs[3]) return;
  int sp = (t >= toffs[1]) + (t >= toffs[2]);
  int by = t - toffs[sp];

  int rstart = offs[sp], rend = offs[sp + 1];
  int r0 = rstart + by * 64;

  int lane = threadIdx.x;
  int n0 = bx * 128;

  const char* Ag = (const char*)A;
  size_t ldab = (size_t)lda_e * 2;
  const char* Bg = (const char*)(BT + (size_t)sp * H_DIM * K);
  size_t ldbb = (size_t)K * 2;

  int l8 = lane >> 3;
  int sw_st = (((lane & 7) ^ l8) << 4);  // inverse-swizzled source byte (involution)

  auto stage = [&](int kt) {
    int k0b = kt * 128;  // kt*64 elems * 2B
#pragma unroll
    for (int c = 0; c < 8; ++c) {
      int row = c * 8 + l8;
      int ar = r0 + row;
      if (ar > rend - 1) ar = rend - 1;
      gload_lds16(Ag + (size_t)ar * ldab + k0b + sw_st, &smem[c * 1024]);
    }
#pragma unroll
    for (int c = 0; c < 16; ++c) {
      int row = c * 8 + l8;
      gload_lds16(Bg + (size_t)(n0 + row) * ldbb + k0b + sw_st, &smem[8192 + c * 1024]);
    }
  };

  f32x4 acc[4][8];
#pragma unroll
  for (int a_ = 0; a_ < 4; ++a_)
#pragma unroll
    for (int b_ = 0; b_ < 8; ++b_) {
      f32x4 z = {0.f, 0.f, 0.f, 0.f};
      acc[a_][b_] = z;
    }

  int lr = lane & 15, lg = lane >> 4;
  int swr = (lr & 7) << 4;

  auto compute = [&]() {
#pragma unroll
    for (int kh = 0; kh < 2; ++kh) {
      int off = (kh * 64 + lg * 16) ^ swr;
      bf16x8 av[4], bv[8];
#pragma unroll
      for (int fm = 0; fm < 4; ++fm)
        av[fm] = *(const bf16x8*)(&smem[(fm * 16 + lr) * 128 + off]);
#pragma unroll
      for (int fn = 0; fn < 8; ++fn)
        bv[fn] = *(const bf16x8*)(&smem[8192 + (fn * 16 + lr) * 128 + off]);
#pragma unroll
      for (int fm = 0; fm < 4; ++fm)
#pragma unroll
        for (int fn = 0; fn < 8; ++fn)
          acc[fm][fn] =
              __builtin_amdgcn_mfma_f32_16x16x32_bf16(av[fm], bv[fn], acc[fm][fn], 0, 0, 0);
    }
  };

  int NT = K / 64;
#pragma unroll 1
  for (int kt = 0; kt < NT; ++kt) {
    stage(kt);
    __syncthreads();
    compute();
    __syncthreads();
  }

  const float* bs = bias + sp * H_DIM;
  if (EPI == 0) {
#pragma unroll
    for (int fm = 0; fm < 4; ++fm)
#pragma unroll
      for (int i = 0; i < 4; ++i) {
        int rr = r0 + fm * 16 + lg * 4 + i;
        if (rr < rend) {
#pragma unroll
          for (int fn = 0; fn < 8; ++fn) {
            int c = n0 + fn * 16 + lr;
            float x = acc[fm][fn][i] + bs[c];
            float h = x / (1.f + __expf(-x));
            Hout[(size_t)rr * H_DIM + c] = (bf16)h;
          }
        }
      }
  } else {
    const float* ws3 = w3 + sp * H_DIM;
    float* ep = e_part + (size_t)bx * N_ATOMS;
#pragma unroll
    for (int fm = 0; fm < 4; ++fm)
#pragma unroll
      for (int i = 0; i < 4; ++i) {
        int rr = r0 + fm * 16 + lg * 4 + i;
        float part = 0.f;
#pragma unroll
        for (int fn = 0; fn < 8; ++fn) {
          int c = n0 + fn * 16 + lr;
          float x = acc[fm][fn][i] + bs[c];
          part += (x / (1.f + __expf(-x))) * ws3[c];
        }
        part += __shfl_xor(part, 1);
        part += __shfl_xor(part, 2);
        part += __shfl_xor(part, 4);
        part += __shfl_xor(part, 8);
        if (lr == 0 && rr < rend) ep[rr] = part;  // non-atomic partial
      }
  }
}

// ---------------- finalize: sum 4 partials, + b3 + comp_w, segment-sum ----------------

__global__ void finalize_kernel(const float* __restrict__ e_part, const int* __restrict__ offs,
                                const float* __restrict__ b3, const float* __restrict__ comp_w,
                                const int* __restrict__ idx_list,
                                const int* __restrict__ struct_id, float* out) {
  __shared__ float bins[NSTRUCT_];
  if (threadIdx.x < NSTRUCT_) bins[threadIdx.x] = 0.f;
  __syncthreads();
  int rr = blockIdx.x * 256 + threadIdx.x;
  if (rr < N_ATOMS) {
    float e = 0.f;
#pragma unroll
    for (int p = 0; p < 4; ++p) e += e_part[(size_t)p * N_ATOMS + rr];
    int s = (rr >= offs[1]) + (rr >= offs[2]);
    e += b3[s] + comp_w[s];
    atomicAdd(&bins[struct_id[idx_list[rr]]], e);
  }
  __syncthreads();
  if (threadIdx.x < NSTRUCT_) atomicAdd(&out[threadIdx.x], bins[threadIdx.x]);
}

// ---------------- launch ----------------

extern "C" void kernel_launch(void* const* d_in, const int* in_sizes, int n_in,
                              void* d_out, int out_size, void* d_ws, size_t ws_size,
                              hipStream_t stream) {
  const float* features = (const float*)d_in[0];
  const float* ln_gamma = (const float*)d_in[1];
  const float* ln_beta = (const float*)d_in[2];
  const float* W1 = (const float*)d_in[3];
  const float* b1 = (const float*)d_in[4];
  const float* W2 = (const float*)d_in[5];
  const float* b2 = (const float*)d_in[6];
  const float* w3 = (const float*)d_in[7];
  const float* b3 = (const float*)d_in[8];
  const float* comp_w = (const float*)d_in[9];
  const int* species = (const int*)d_in[10];
  const int* struct_id = (const int*)d_in[11];
  float* out = (float*)d_out;

  char* ws = (char*)d_ws;
  size_t off = 0;
  auto alloc = [&](size_t bytes) {
    char* p = ws + off;
    off += (bytes + 255) & ~(size_t)255;
    return p;
  };
  bf16* W1T = (bf16*)alloc((size_t)S_NUM * H_DIM * F_DIM * 2);
  bf16* W2T = (bf16*)alloc((size_t)S_NUM * H_DIM * H_DIM * 2);
  bf16* xln = (bf16*)alloc((size_t)N_ATOMS * F_DIM * 2);
  bf16* h1 = (bf16*)alloc((size_t)N_ATOMS * H_DIM * 2);
  float* e_part = (float*)alloc((size_t)4 * N_ATOMS * 4);
  int* idx_list = (int*)alloc((size_t)N_ATOMS * 4);
  int* pos_of = (int*)alloc((size_t)N_ATOMS * 4);
  int* ints = (int*)alloc(64);
  int* pos = ints;
  int* offs = ints + 6;
  int* toffs = ints + 10;

  int nb = (N_ATOMS + 255) / 256;
  count_offs_kernel<<<1, 1024, 0, stream>>>(species, ints, out);
  scatter_kernel<<<nb, 256, 0, stream>>>(species, pos, offs, idx_list, pos_of);
  transpose_kernel<<<912, 256, 0, stream>>>(W1, W1T, W2, W2T);
  ln_kernel<<<N_ATOMS, 256, 0, stream>>>(features, ln_gamma, ln_beta, species, pos_of, xln);

  gemm_kernel<0><<<4 * MAXT64, 64, 0, stream>>>(xln, F_DIM, W1T, F_DIM, b1, nullptr, h1,
                                                nullptr, offs, toffs);
  gemm_kernel<1><<<4 * MAXT64, 64, 0, stream>>>(h1, H_DIM, W2T, H_DIM, b2, w3, nullptr,
                                                e_part, offs, toffs);
  finalize_kernel<<<nb, 256, 0, stream>>>(e_part, offs, b3, comp_w, idx_list, struct_id, out);
}

// Round 7
// 145.402 us; speedup vs baseline: 3.8832x; 1.0497x over previous
//
#include <hip/hip_runtime.h>
#include <cstdint>
#include <cstddef>

#define N_ATOMS 20000
#define F_DIM 1920
#define H_DIM 512
#define S_NUM 3
#define NSTRUCT_ 16
#define MAXT64 315  // ceil(20000/64) + (S_NUM-1)
#define NCNT 8      // count blocks in prep kernel

typedef __bf16 bf16;
typedef __bf16 bf16x4 __attribute__((ext_vector_type(4)));
typedef __bf16 bf16x8 __attribute__((ext_vector_type(8)));
typedef float f32x4 __attribute__((ext_vector_type(4)));

__device__ __forceinline__ void gload_lds16(const void* g, void* l) {
  __builtin_amdgcn_global_load_lds(
      (const __attribute__((address_space(1))) unsigned int*)g,
      (__attribute__((address_space(3))) unsigned int*)l, 16, 0, 0);
}

// ints layout (in d_ws): pos[0..2] @0, offs[4] @6, toffs[4] @10, cnt8[8][3] @16
#define CNT8_OFF 16

// ---------------- prep: W1/W2 transpose+cast (912 blocks) + count (8 blocks) ----
// Count blocks write per-block plain-store count slots: no atomics, no zero-init
// dependency (every slot written every launch -> deterministic under poison).
__global__ __launch_bounds__(256) void prep_kernel(const float* __restrict__ W1,
                                                   bf16* __restrict__ W1T,
                                                   const float* __restrict__ W2,
                                                   bf16* __restrict__ W2T,
                                                   const int* __restrict__ species,
                                                   int* ints, float* out) {
  int id = blockIdx.x;
  if (id >= 912) {
    // ---- count block ----
    int cb = id - 912;  // 0..7
    int tid = threadIdx.x;
    if (cb == 0) {
      if (tid < 3) ints[tid] = 0;            // pos[s] = 0 (used only after prep)
      if (tid < NSTRUCT_) out[tid] = 0.f;    // final output accumulators
    }
    int base = cb * (N_ATOMS / NCNT);
    int end = base + (N_ATOMS / NCNT);
    int c0 = 0, c1 = 0, c2 = 0;
    for (int i = base + tid; i < end; i += 256) {
      int s = species[i];
      c0 += (s == 0);
      c1 += (s == 1);
      c2 += (s == 2);
    }
#pragma unroll
    for (int m = 1; m < 64; m <<= 1) {
      c0 += __shfl_xor(c0, m);
      c1 += __shfl_xor(c1, m);
      c2 += __shfl_xor(c2, m);
    }
    __shared__ int red[4][3];
    if ((tid & 63) == 0) {
      red[tid >> 6][0] = c0;
      red[tid >> 6][1] = c1;
      red[tid >> 6][2] = c2;
    }
    __syncthreads();
    if (tid == 0) {
      int* slot = ints + CNT8_OFF + cb * 3;
      slot[0] = red[0][0] + red[1][0] + red[2][0] + red[3][0];
      slot[1] = red[0][1] + red[1][1] + red[2][1] + red[3][1];
      slot[2] = red[0][2] + red[1][2] + red[2][2] + red[3][2];
    }
    return;
  }
  // ---- transpose block ----
  __shared__ float tile[64][65];
  const float* ins;
  bf16* outs;
  int R, C, r0, c0;
  if (id < 720) {
    int sp = id / 240, rem = id % 240;
    R = F_DIM;
    C = H_DIM;
    c0 = (rem & 7) * 64;
    r0 = (rem >> 3) * 64;
    ins = W1 + (size_t)sp * R * C;
    outs = W1T + (size_t)sp * R * C;
  } else {
    int id2 = id - 720;
    int sp = id2 / 64, rem = id2 % 64;
    R = H_DIM;
    C = H_DIM;
    c0 = (rem & 7) * 64;
    r0 = (rem >> 3) * 64;
    ins = W2 + (size_t)sp * R * C;
    outs = W2T + (size_t)sp * R * C;
  }
  int tc = threadIdx.x & 63, tr4 = threadIdx.x >> 6;
#pragma unroll
  for (int it = 0; it < 16; ++it) {
    int r = it * 4 + tr4;
    tile[r][tc] = ins[(size_t)(r0 + r) * C + c0 + tc];
  }
  __syncthreads();
#pragma unroll
  for (int it = 0; it < 16; ++it) {
    int oc = it * 4 + tr4;
    outs[(size_t)(c0 + oc) * R + r0 + tc] = (bf16)tile[tc][oc];
  }
}

// ---------------- scatter: derive offs locally, ballot-aggregated placement ----

__global__ void scatter_kernel(const int* __restrict__ species, int* ints,
                               int* idx_list, int* pos_of) {
  // every block derives offs/toffs from the 8x3 count slots (kernel boundary
  // guarantees prep completed)
  int n0 = 0, n1 = 0, n2 = 0;
#pragma unroll
  for (int b = 0; b < NCNT; ++b) {
    const int* slot = ints + CNT8_OFF + b * 3;
    n0 += slot[0];
    n1 += slot[1];
    n2 += slot[2];
  }
  int offs_l[4] = {0, n0, n0 + n1, N_ATOMS};
  if (blockIdx.x == 0 && threadIdx.x == 0) {
    int* offs = ints + 6;
    int* toffs = ints + 10;
    offs[0] = 0;
    offs[1] = n0;
    offs[2] = n0 + n1;
    offs[3] = N_ATOMS;
    int t0 = (n0 + 63) >> 6, t1 = (n1 + 63) >> 6, t2 = (n2 + 63) >> 6;
    toffs[0] = 0;
    toffs[1] = t0;
    toffs[2] = t0 + t1;
    toffs[3] = t0 + t1 + t2;
  }
  int* pos = ints;
  int i = blockIdx.x * 256 + threadIdx.x;
  int lane = threadIdx.x & 63;
  int sp = (i < N_ATOMS) ? species[i] : -1;
#pragma unroll
  for (int s = 0; s < S_NUM; ++s) {
    unsigned long long mask = __ballot(sp == s);
    if (!mask) continue;
    int leader = __ffsll((long long)mask) - 1;
    int base = 0;
    if (lane == leader) base = atomicAdd(&pos[s], __popcll(mask));
    base = __shfl(base, leader);
    if (sp == s) {
      int rank = __popcll(mask & ((1ULL << lane) - 1ULL));
      int p = offs_l[s] + base + rank;
      idx_list[p] = i;
      pos_of[i] = p;
    }
  }
}

// ---------------- LayerNorm (writes bf16 rows in permuted order) ----------------

__global__ __launch_bounds__(256) void ln_kernel(
    const float* __restrict__ feat, const float* __restrict__ gamma,
    const float* __restrict__ beta, const int* __restrict__ species,
    const int* __restrict__ pos_of, bf16* __restrict__ xln) {
  int atom = blockIdx.x, tid = threadIdx.x;
  const float4* frow = (const float4*)(feat + (size_t)atom * F_DIM);
  float4 v0 = frow[tid];
  bool has2 = tid < 224;
  float4 v1 = has2 ? frow[256 + tid] : make_float4(0.f, 0.f, 0.f, 0.f);
  float s = v0.x + v0.y + v0.z + v0.w;
  float s2 = v0.x * v0.x + v0.y * v0.y + v0.z * v0.z + v0.w * v0.w;
  if (has2) {
    s += v1.x + v1.y + v1.z + v1.w;
    s2 += v1.x * v1.x + v1.y * v1.y + v1.z * v1.z + v1.w * v1.w;
  }
#pragma unroll
  for (int m = 1; m < 64; m <<= 1) {
    s += __shfl_xor(s, m);
    s2 += __shfl_xor(s2, m);
  }
  __shared__ float red[4][2];
  if ((tid & 63) == 0) { red[tid >> 6][0] = s; red[tid >> 6][1] = s2; }
  __syncthreads();
  s = red[0][0] + red[1][0] + red[2][0] + red[3][0];
  s2 = red[0][1] + red[1][1] + red[2][1] + red[3][1];
  float mu = s * (1.f / F_DIM);
  float var = s2 * (1.f / F_DIM) - mu * mu;
  float rsig = rsqrtf(var + 1e-5f);
  int sp = species[atom];
  size_t p = (size_t)pos_of[atom];
  const float4* g4 = (const float4*)(gamma + (size_t)sp * F_DIM);
  const float4* b4 = (const float4*)(beta + (size_t)sp * F_DIM);
  bf16* orow = xln + p * F_DIM;
  {
    float4 g = g4[tid], b = b4[tid];
    bf16x4 o;
    o[0] = (bf16)((v0.x - mu) * rsig * g.x + b.x);
    o[1] = (bf16)((v0.y - mu) * rsig * g.y + b.y);
    o[2] = (bf16)((v0.z - mu) * rsig * g.z + b.z);
    o[3] = (bf16)((v0.w - mu) * rsig * g.w + b.w);
    *(bf16x4*)(orow + 4 * tid) = o;
  }
  if (has2) {
    float4 g = g4[256 + tid], b = b4[256 + tid];
    bf16x4 o;
    o[0] = (bf16)((v1.x - mu) * rsig * g.x + b.x);
    o[1] = (bf16)((v1.y - mu) * rsig * g.y + b.y);
    o[2] = (bf16)((v1.z - mu) * rsig * g.z + b.z);
    o[3] = (bf16)((v1.w - mu) * rsig * g.w + b.w);
    *(bf16x4*)(orow + 4 * (256 + tid)) = o;
  }
}

// ---------------- bf16 MFMA GEMM, single-wave block, 64x128 tile, BK=64 ----------
// A: [rows][lda_e] bf16 (permuted). BT: [S][512][K] bf16.
// EPI 0: Hout[r][c] = silu(acc + bias[c])
// EPI 1: e_part[bx][r] = sum_c silu(acc + bias[c]) * w3[c]  (plain store)

template <int EPI>
__global__ __launch_bounds__(64, 2) void gemm_kernel(
    const bf16* __restrict__ A, int lda_e, const bf16* __restrict__ BT, int K,
    const float* __restrict__ bias, const float* __restrict__ w3,
    bf16* __restrict__ Hout, float* __restrict__ e_part,
    const int* __restrict__ ints) {
  __shared__ char smem[24576];  // A: 64x64 bf16 @0 (8KB), B: 128x64 @8192 (16KB)
  const int* offs = ints + 6;
  const int* toffs = ints + 10;

  int total = gridDim.x;
  int lid = blockIdx.x;
  // bijective XCD-chunk swizzle (m204)
  int q = total >> 3, r = total & 7;
  int xcd = lid & 7, sl = lid >> 3;
  int w = (xcd < r ? xcd * (q + 1) : r * (q + 1) + (xcd - r) * q) + sl;
  int bx = w & 3;
  int t = w >> 2;
  if (t >= toffs[3]) return;
  int sp = (t >= toffs[1]) + (t >= toffs[2]);
  int by = t - toffs[sp];

  int rstart = offs[sp], rend = offs[sp + 1];
  int r0 = rstart + by * 64;

  int lane = threadIdx.x;
  int n0 = bx * 128;

  const char* Ag = (const char*)A;
  size_t ldab = (size_t)lda_e * 2;
  const char* Bg = (const char*)(BT + (size_t)sp * H_DIM * K);
  size_t ldbb = (size_t)K * 2;

  int l8 = lane >> 3;
  int sw_st = (((lane & 7) ^ l8) << 4);  // inverse-swizzled source byte (involution)

  auto stage = [&](int kt) {
    int k0b = kt * 128;  // kt*64 elems * 2B
#pragma unroll
    for (int c = 0; c < 8; ++c) {
      int row = c * 8 + l8;
      int ar = r0 + row;
      if (ar > rend - 1) ar = rend - 1;
      gload_lds16(Ag + (size_t)ar * ldab + k0b + sw_st, &smem[c * 1024]);
    }
#pragma unroll
    for (int c = 0; c < 16; ++c) {
      int row = c * 8 + l8;
      gload_lds16(Bg + (size_t)(n0 + row) * ldbb + k0b + sw_st, &smem[8192 + c * 1024]);
    }
  };

  f32x4 acc[4][8];
#pragma unroll
  for (int a_ = 0; a_ < 4; ++a_)
#pragma unroll
    for (int b_ = 0; b_ < 8; ++b_) {
      f32x4 z = {0.f, 0.f, 0.f, 0.f};
      acc[a_][b_] = z;
    }

  int lr = lane & 15, lg = lane >> 4;
  int swr = (lr & 7) << 4;

  auto compute = [&]() {
#pragma unroll
    for (int kh = 0; kh < 2; ++kh) {
      int off = (kh * 64 + lg * 16) ^ swr;
      bf16x8 av[4], bv[8];
#pragma unroll
      for (int fm = 0; fm < 4; ++fm)
        av[fm] = *(const bf16x8*)(&smem[(fm * 16 + lr) * 128 + off]);
#pragma unroll
      for (int fn = 0; fn < 8; ++fn)
        bv[fn] = *(const bf16x8*)(&smem[8192 + (fn * 16 + lr) * 128 + off]);
#pragma unroll
      for (int fm = 0; fm < 4; ++fm)
#pragma unroll
        for (int fn = 0; fn < 8; ++fn)
          acc[fm][fn] =
              __builtin_amdgcn_mfma_f32_16x16x32_bf16(av[fm], bv[fn], acc[fm][fn], 0, 0, 0);
    }
  };

  int NT = K / 64;
#pragma unroll 1
  for (int kt = 0; kt < NT; ++kt) {
    stage(kt);
    __syncthreads();
    compute();
    __syncthreads();
  }

  const float* bs = bias + sp * H_DIM;
  if (EPI == 0) {
#pragma unroll
    for (int fm = 0; fm < 4; ++fm)
#pragma unroll
      for (int i = 0; i < 4; ++i) {
        int rr = r0 + fm * 16 + lg * 4 + i;
        if (rr < rend) {
#pragma unroll
          for (int fn = 0; fn < 8; ++fn) {
            int c = n0 + fn * 16 + lr;
            float x = acc[fm][fn][i] + bs[c];
            float h = x / (1.f + __expf(-x));
            Hout[(size_t)rr * H_DIM + c] = (bf16)h;
          }
        }
      }
  } else {
    const float* ws3 = w3 + sp * H_DIM;
    float* ep = e_part + (size_t)bx * N_ATOMS;
#pragma unroll
    for (int fm = 0; fm < 4; ++fm)
#pragma unroll
      for (int i = 0; i < 4; ++i) {
        int rr = r0 + fm * 16 + lg * 4 + i;
        float part = 0.f;
#pragma unroll
        for (int fn = 0; fn < 8; ++fn) {
          int c = n0 + fn * 16 + lr;
          float x = acc[fm][fn][i] + bs[c];
          part += (x / (1.f + __expf(-x))) * ws3[c];
        }
        part += __shfl_xor(part, 1);
        part += __shfl_xor(part, 2);
        part += __shfl_xor(part, 4);
        part += __shfl_xor(part, 8);
        if (lr == 0 && rr < rend) ep[rr] = part;  // non-atomic partial
      }
  }
}

// ---------------- finalize: sum 4 partials, + b3 + comp_w, segment-sum ----------------

__global__ void finalize_kernel(const float* __restrict__ e_part, const int* __restrict__ ints,
                                const float* __restrict__ b3, const float* __restrict__ comp_w,
                                const int* __restrict__ idx_list,
                                const int* __restrict__ struct_id, float* out) {
  const int* offs = ints + 6;
  __shared__ float bins[NSTRUCT_];
  if (threadIdx.x < NSTRUCT_) bins[threadIdx.x] = 0.f;
  __syncthreads();
  int rr = blockIdx.x * 256 + threadIdx.x;
  if (rr < N_ATOMS) {
    float e = 0.f;
#pragma unroll
    for (int p = 0; p < 4; ++p) e += e_part[(size_t)p * N_ATOMS + rr];
    int s = (rr >= offs[1]) + (rr >= offs[2]);
    e += b3[s] + comp_w[s];
    atomicAdd(&bins[struct_id[idx_list[rr]]], e);
  }
  __syncthreads();
  if (threadIdx.x < NSTRUCT_) atomicAdd(&out[threadIdx.x], bins[threadIdx.x]);
}

// ---------------- launch ----------------

extern "C" void kernel_launch(void* const* d_in, const int* in_sizes, int n_in,
                              void* d_out, int out_size, void* d_ws, size_t ws_size,
                              hipStream_t stream) {
  const float* features = (const float*)d_in[0];
  const float* ln_gamma = (const float*)d_in[1];
  const float* ln_beta = (const float*)d_in[2];
  const float* W1 = (const float*)d_in[3];
  const float* b1 = (const float*)d_in[4];
  const float* W2 = (const float*)d_in[5];
  const float* b2 = (const float*)d_in[6];
  const float* w3 = (const float*)d_in[7];
  const float* b3 = (const float*)d_in[8];
  const float* comp_w = (const float*)d_in[9];
  const int* species = (const int*)d_in[10];
  const int* struct_id = (const int*)d_in[11];
  float* out = (float*)d_out;

  char* ws = (char*)d_ws;
  size_t off = 0;
  auto alloc = [&](size_t bytes) {
    char* p = ws + off;
    off += (bytes + 255) & ~(size_t)255;
    return p;
  };
  bf16* W1T = (bf16*)alloc((size_t)S_NUM * H_DIM * F_DIM * 2);
  bf16* W2T = (bf16*)alloc((size_t)S_NUM * H_DIM * H_DIM * 2);
  bf16* xln = (bf16*)alloc((size_t)N_ATOMS * F_DIM * 2);
  bf16* h1 = (bf16*)alloc((size_t)N_ATOMS * H_DIM * 2);
  float* e_part = (float*)alloc((size_t)4 * N_ATOMS * 4);
  int* idx_list = (int*)alloc((size_t)N_ATOMS * 4);
  int* pos_of = (int*)alloc((size_t)N_ATOMS * 4);
  int* ints = (int*)alloc(256);

  int nb = (N_ATOMS + 255) / 256;
  prep_kernel<<<912 + NCNT, 256, 0, stream>>>(W1, W1T, W2, W2T, species, ints, out);
  scatter_kernel<<<nb, 256, 0, stream>>>(species, ints, idx_list, pos_of);
  ln_kernel<<<N_ATOMS, 256, 0, stream>>>(features, ln_gamma, ln_beta, species, pos_of, xln);

  gemm_kernel<0><<<4 * MAXT64, 64, 0, stream>>>(xln, F_DIM, W1T, F_DIM, b1, nullptr, h1,
                                                nullptr, ints);
  gemm_kernel<1><<<4 * MAXT64, 64, 0, stream>>>(h1, H_DIM, W2T, H_DIM, b2, w3, nullptr,
                                                e_part, ints);
  finalize_kernel<<<nb, 256, 0, stream>>>(e_part, ints, b3, comp_w, idx_list, struct_id, out);
}